// Round 3
// baseline (581.122 us; speedup 1.0000x reference)
//
#include <hip/hip_runtime.h>
#include <math.h>

#define N_PTS 300000
#define NJ 80          // K joints
#define FDIM 64        // feature dim
#define VN 6890        // smpl verts
#define TILE 256
#define NTILES ((N_PTS + TILE - 1) / TILE)   // 1172

#define AQ(V, Q) ((Q)==0 ? (V).x : (Q)==1 ? (V).y : (Q)==2 ? (V).z : (V).w)

// ---------------------------------------------------------------------------
// kA: fused  a = softmax(-sqdist(feature, centers))  and
//            jacc[k][c] += sum_n a[n][k] * data[n][c]
//     data cols: 0..63 = feature, 64..66 = xyz, 67 = 1 (cnt)
// All-LDS design: centers staged once; per 64-pt chunk:
//   stage d-tile -> GEMM1 (logits, reg-tiled) -> shfl softmax -> s_at
//   -> GEMM2 (reg-tiled) accumulating jacc outputs.
// No global loads inside inner loops.
// ---------------------------------------------------------------------------
__global__ __launch_bounds__(256) void kA(
    const float* __restrict__ xyz, const float* __restrict__ feature,
    const float* __restrict__ centers, float* __restrict__ jacc)
{
  __shared__ float s_c[NJ][68];     // centers, row pad 68 -> 2-way banks (free)
  __shared__ float s_cn[NJ];        // |c_k|^2
  __shared__ float s_at[NJ][68];    // softmax weights transposed [k][n]
  __shared__ float s_d[64][68];     // data chunk natural [n][c]

  const int tid  = threadIdx.x;
  const int wid  = tid >> 6;
  const int kt   = tid & 15;        // k-lane
  const int nt   = tid >> 4;        // n-lane / c-lane (GEMM2)
  const int base = blockIdx.x * TILE;

  // ---- stage centers once ----
  for (int idx = tid; idx < NJ * 16; idx += 256) {
    int k = idx >> 4, q = idx & 15;
    float4 v = ((const float4*)centers)[k * 16 + q];
    *(float4*)&s_c[k][4 * q] = v;
  }
  __syncthreads();
  if (tid < NJ) {
    float s = 0.f;
    for (int q = 0; q < 16; ++q) {
      float4 v = *(const float4*)&s_c[tid][4 * q];
      s += v.x*v.x + v.y*v.y + v.z*v.z + v.w*v.w;
    }
    s_cn[tid] = s;
  }

  // persistent GEMM2 accumulators
  float acc[5][4];
  #pragma unroll
  for (int i = 0; i < 5; ++i)
    #pragma unroll
    for (int j = 0; j < 4; ++j) acc[i][j] = 0.f;
  float accE0 = 0.f, accE1 = 0.f;
  const int k0e = kt + 16 * wid;    // wave-uniform row for extras
  const int ce0 = nt & 3;

  for (int s4 = 0; s4 < 4; ++s4) {
    __syncthreads();   // prev chunk fully consumed; also covers s_cn/s_c init
    // ---- stage d-tile (64 points x 68 cols) ----
    {
      const int r = tid >> 2;
      const int gn = base + s4 * 64 + r;
      #pragma unroll
      for (int ii = 0; ii < 5; ++ii) {
        const int cc = (tid & 3) + 4 * ii;
        if (cc < 17) {
          float4 v = make_float4(0.f, 0.f, 0.f, 0.f);
          if (gn < N_PTS) {
            if (cc < 16) v = ((const float4*)(feature + (size_t)gn * FDIM))[cc];
            else v = make_float4(xyz[3*gn], xyz[3*gn+1], xyz[3*gn+2], 1.f);
          }
          *(float4*)&s_d[r][4 * cc] = v;
        }
      }
    }
    __syncthreads();

    // ---- GEMM1: logits acc1[i][j] = f(n=nt+16j) . c(k=kt+16i) ----
    float acc1[5][4];
    #pragma unroll
    for (int i = 0; i < 5; ++i)
      #pragma unroll
      for (int j = 0; j < 4; ++j) acc1[i][j] = 0.f;

    #pragma unroll 2
    for (int d0 = 0; d0 < FDIM; d0 += 4) {
      float4 cv[5], fv[4];
      #pragma unroll
      for (int i = 0; i < 5; ++i) cv[i] = *(const float4*)&s_c[kt + 16*i][d0];
      #pragma unroll
      for (int j = 0; j < 4; ++j) fv[j] = *(const float4*)&s_d[nt + 16*j][d0];
      #pragma unroll
      for (int i = 0; i < 5; ++i)
        #pragma unroll
        for (int j = 0; j < 4; ++j)
          acc1[i][j] += cv[i].x*fv[j].x + cv[i].y*fv[j].y
                      + cv[i].z*fv[j].z + cv[i].w*fv[j].w;
    }

    // ---- softmax over k (80) per point; k split over 16 kt lanes x 5 ----
    #pragma unroll
    for (int j = 0; j < 4; ++j) {
      float l[5];
      #pragma unroll
      for (int i = 0; i < 5; ++i) l[i] = 2.f * acc1[i][j] - s_cn[kt + 16*i];
      float m = l[0];
      #pragma unroll
      for (int i = 1; i < 5; ++i) m = fmaxf(m, l[i]);
      #pragma unroll
      for (int ms = 1; ms < 16; ms <<= 1) m = fmaxf(m, __shfl_xor(m, ms));
      float e[5], s = 0.f;
      #pragma unroll
      for (int i = 0; i < 5; ++i) { e[i] = __expf(l[i] - m); s += e[i]; }
      #pragma unroll
      for (int ms = 1; ms < 16; ms <<= 1) s += __shfl_xor(s, ms);
      float rs = 1.f / s;
      #pragma unroll
      for (int i = 0; i < 5; ++i) s_at[kt + 16*i][nt + 16*j] = e[i] * rs;
    }
    __syncthreads();

    // ---- GEMM2: jacc[80][68] += a^T * d ----
    #pragma unroll 2
    for (int nn = 0; nn < 64; nn += 4) {
      float4 av[5], dv[4];
      #pragma unroll
      for (int i = 0; i < 5; ++i) av[i] = *(const float4*)&s_at[kt + 16*i][nn];
      #pragma unroll
      for (int q = 0; q < 4; ++q) dv[q] = *(const float4*)&s_d[nn + q][4 * nt];
      #pragma unroll
      for (int i = 0; i < 5; ++i) {
        #pragma unroll
        for (int q = 0; q < 4; ++q) {
          const float aq = AQ(av[i], q);
          acc[i][0] += aq * dv[q].x;
          acc[i][1] += aq * dv[q].y;
          acc[i][2] += aq * dv[q].z;
          acc[i][3] += aq * dv[q].w;
        }
      }
      {
        float4 ae = *(const float4*)&s_at[k0e][nn];
        #pragma unroll
        for (int q = 0; q < 4; ++q)
          accE0 += AQ(ae, q) * s_d[nn + q][64 + ce0];
      }
      if (tid < 64) {
        float4 ae = *(const float4*)&s_at[64 + kt][nn];
        #pragma unroll
        for (int q = 0; q < 4; ++q)
          accE1 += AQ(ae, q) * s_d[nn + q][64 + nt];
      }
    }
  }

  #pragma unroll
  for (int i = 0; i < 5; ++i)
    #pragma unroll
    for (int j = 0; j < 4; ++j)
      atomicAdd(&jacc[(kt + 16*i) * 68 + 4*nt + j], acc[i][j]);
  atomicAdd(&jacc[k0e * 68 + 64 + ce0], accE0);
  if (tid < 64) atomicAdd(&jacc[(64 + kt) * 68 + 64 + nt], accE1);
}

// ---------------------------------------------------------------------------
// kB: fused finalize + lohi + argmin + full joint MLP chain (one block, 512t)
// ---------------------------------------------------------------------------
__global__ __launch_bounds__(512) void kB(
    const float* __restrict__ jacc, const float* __restrict__ smpl,
    const float* __restrict__ sw, const float* __restrict__ bpf,
    const float* __restrict__ w_body, const float* __restrict__ b_body,
    const float* __restrict__ w_pos1, const float* __restrict__ b_pos1,
    const float* __restrict__ w_pos2, const float* __restrict__ b_pos2,
    const float* __restrict__ w_rot,  const float* __restrict__ b_rot,
    const float* __restrict__ w_trans,const float* __restrict__ b_trans,
    float* __restrict__ jpack, float* __restrict__ qpack,
    float* __restrict__ tpack)
{
  // shared aliasing: bufA(10240) | bufB/jfeatL(5440) | jpackL(320) | lohi(8) | idx(80)
  __shared__ float sh[16088];
  float* bufA   = sh;            // 80*128; also aliased as red[512*6] early
  float* bufB   = sh + 10240;    // 80*68 ; aliased as jfeatL (80*64) early
  float* jfeatL = sh + 10240;
  float* jpackL = sh + 15680;    // 80*4
  float* lohiL  = sh + 16000;    // 6
  int*   idxL   = (int*)(sh + 16008); // 80

  const int tid = threadIdx.x;

  // ---- finalize joints from jacc ----
  for (int i = tid; i < NJ * 68; i += 512) {
    int k = i / 68, c = i % 68;
    if (c == 67) continue;
    float cnt = jacc[k * 68 + 67] + 1e-6f;
    float v = jacc[i] / cnt;
    if (c < 64) jfeatL[k * 64 + c] = v;
    else        jpackL[k * 4 + (c - 64)] = v;
  }
  __syncthreads();
  if (tid < NJ) {
    float x = jpackL[tid*4], y = jpackL[tid*4+1], z = jpackL[tid*4+2];
    float w = x*x + y*y + z*z;
    jpackL[tid*4+3] = w;
    *(float4*)&jpack[tid*4] = make_float4(x, y, z, w);
  }

  // ---- lo/hi over smpl verts (red aliases bufA) ----
  {
    float lo[3] = {1e30f,1e30f,1e30f}, hi[3] = {-1e30f,-1e30f,-1e30f};
    for (int v = tid; v < VN; v += 512)
      for (int c = 0; c < 3; ++c) {
        float t = smpl[v*3+c];
        lo[c] = fminf(lo[c], t); hi[c] = fmaxf(hi[c], t);
      }
    float* red = bufA;
    for (int c = 0; c < 3; ++c) { red[tid*6+c] = lo[c]; red[tid*6+3+c] = hi[c]; }
    __syncthreads();
    for (int off = 256; off > 0; off >>= 1) {
      if (tid < off)
        for (int c = 0; c < 3; ++c) {
          red[tid*6+c]   = fminf(red[tid*6+c],   red[(tid+off)*6+c]);
          red[tid*6+3+c] = fmaxf(red[tid*6+3+c], red[(tid+off)*6+3+c]);
        }
      __syncthreads();
    }
    if (tid < 6) lohiL[tid] = red[tid];
    __syncthreads();
  }

  // ---- argmin: 10 passes x 8 joints, one wave per joint, shfl reduce ----
  {
    const int lane = tid & 63;
    for (int pass = 0; pass < 10; ++pass) {
      const int k = pass * 8 + (tid >> 6);
      const float jx = jpackL[k*4], jy = jpackL[k*4+1], jz = jpackL[k*4+2];
      float best = 1e30f; int bi = 0;
      for (int v = lane; v < VN; v += 64) {
        float dx = smpl[v*3]   - jx;
        float dy = smpl[v*3+1] - jy;
        float dz = smpl[v*3+2] - jz;
        float d = dx*dx + dy*dy + dz*dz;
        if (d < best) { best = d; bi = v; }
      }
      for (int m = 1; m < 64; m <<= 1) {
        float d2 = __shfl_xor(best, m); int i2 = __shfl_xor(bi, m);
        if (d2 < best || (d2 == best && i2 < bi)) { best = d2; bi = i2; }
      }
      if (lane == 0) idxL[k] = bi;
    }
  }
  __syncthreads();

  // ---- layer 0: g_in = [body_feat | joint_feat] -> bufA[80][128] ----
  for (int o = tid; o < NJ * 128; o += 512) {
    int k = o >> 7, c = o & 127;
    float v;
    if (c < 64) {
      int vid = idxL[k];
      float s = 0.f;
      for (int j = 0; j < 24; ++j) s += sw[vid * 24 + j] * bpf[j * 64 + c];
      v = s;
    } else {
      v = jfeatL[k * 64 + (c - 64)];
    }
    bufA[o] = v;
  }
  __syncthreads();

  // ---- layer 1: gelu(g_in @ w_body + b) -> bufB[k][3+m]; xn -> bufB[k][0..2]
  for (int o = tid; o < NJ * 64; o += 512) {
    int k = o >> 6, m = o & 63;
    float s = b_body[m];
    for (int i = 0; i < 128; ++i) s += bufA[k*128 + i] * w_body[i * 64 + m];
    float u = 0.7978845608028654f * (s + 0.044715f * s * s * s);
    float e = __expf(2.f * u);
    float th = 1.f - 2.f / (e + 1.f);
    bufB[k*68 + 3 + m] = 0.5f * s * (1.f + th);
  }
  if (tid < NJ * 3) {
    int k = tid / 3, c = tid % 3;
    float lo = lohiL[c], hi = lohiL[3 + c];
    bufB[k*68 + c] = 2.f * (jpackL[k * 4 + c] - lo) / (hi - lo + 1e-6f) - 1.f;
  }
  __syncthreads();

  // ---- layer 2: h = relu([xn|g] @ w_pos1 + b) -> bufA[80][128] ----
  for (int o = tid; o < NJ * 128; o += 512) {
    int k = o >> 7, m = o & 127;
    float s = b_pos1[m];
    for (int i = 0; i < 67; ++i) s += bufB[k*68 + i] * w_pos1[i * 128 + m];
    bufA[o] = fmaxf(s, 0.f);
  }
  __syncthreads();

  // ---- layer 3: g2 = h @ w_pos2 + b -> bufB[k][0..63] ----
  for (int o = tid; o < NJ * 64; o += 512) {
    int k = o >> 6, m = o & 63;
    float s = b_pos2[m];
    for (int i = 0; i < 128; ++i) s += bufA[k*128 + i] * w_pos2[i * 64 + m];
    bufB[k*68 + m] = s;
  }
  __syncthreads();

  // ---- layer 4: q (normalized) and t ----
  if (tid < NJ) {
    int k = tid;
    float q[4];
    for (int j = 0; j < 4; ++j) {
      float s = b_rot[j];
      for (int i = 0; i < 64; ++i) s += bufB[k*68 + i] * w_rot[i * 4 + j];
      q[j] = s;
    }
    float nrm = sqrtf(q[0]*q[0]+q[1]*q[1]+q[2]*q[2]+q[3]*q[3]) + 1e-6f;
    float rn = 1.f / nrm;
    *(float4*)&qpack[k*4] = make_float4(q[0]*rn, q[1]*rn, q[2]*rn, q[3]*rn);
    float t[3];
    for (int j = 0; j < 3; ++j) {
      float s = b_trans[j];
      for (int i = 0; i < 64; ++i) s += bufB[k*68 + i] * w_trans[i * 3 + j];
      t[j] = s;
    }
    *(float4*)&tpack[k*4] = make_float4(t[0], t[1], t[2], 0.f);
  }
}

// ---------------------------------------------------------------------------
// kC: per-point joint softmax + quaternion blend (joint tables in LDS)
// ---------------------------------------------------------------------------
__global__ __launch_bounds__(256) void kC(
    const float* __restrict__ xyz, const float* __restrict__ jpack,
    const float* __restrict__ qpack, const float* __restrict__ tpack,
    float* __restrict__ out)
{
  __shared__ float4 sj[NJ], sq[NJ], st[NJ];
  const int tid = threadIdx.x;
  if (tid < 80)        sj[tid]       = ((const float4*)jpack)[tid];
  else if (tid < 160)  sq[tid - 80]  = ((const float4*)qpack)[tid - 80];
  else if (tid < 240)  st[tid - 160] = ((const float4*)tpack)[tid - 160];
  __syncthreads();

  const int p = blockIdx.x * 256 + tid;
  if (p >= N_PTS) return;

  float x0 = xyz[p*3], x1 = xyz[p*3+1], x2 = xyz[p*3+2];
  float l[NJ];
  float m = -1e30f;
  #pragma unroll
  for (int k = 0; k < NJ; ++k) {
    float4 j = sj[k];
    l[k] = (2.f*(x0*j.x + x1*j.y + x2*j.z) - j.w) * 10.0f;  // 1/SIGMA
    m = fmaxf(m, l[k]);
  }
  float s = 0.f;
  float qb0=0,qb1=0,qb2=0,qb3=0, tb0=0,tb1=0,tb2=0;
  #pragma unroll
  for (int k = 0; k < NJ; ++k) {
    float e = __expf(l[k] - m);
    s += e;
    float4 q = sq[k];
    float4 t = st[k];
    qb0 += e*q.x; qb1 += e*q.y; qb2 += e*q.z; qb3 += e*q.w;
    tb0 += e*t.x; tb1 += e*t.y; tb2 += e*t.z;
  }
  float rs = 1.f / s;
  qb0*=rs; qb1*=rs; qb2*=rs; qb3*=rs; tb0*=rs; tb1*=rs; tb2*=rs;
  float nrm = sqrtf(qb0*qb0+qb1*qb1+qb2*qb2+qb3*qb3) + 1e-6f;
  float rn = 1.f / nrm;
  float qw = qb0*rn, qx = qb1*rn, qy = qb2*rn, qz = qb3*rn;
  float t2x = 2.f*(qy*x2 - qz*x1);
  float t2y = 2.f*(qz*x0 - qx*x2);
  float t2z = 2.f*(qx*x1 - qy*x0);
  float cx = qy*t2z - qz*t2y;
  float cy = qz*t2x - qx*t2z;
  float cz = qx*t2y - qy*t2x;
  out[p*3]   = x0 + qw*t2x + cx + tb0;
  out[p*3+1] = x1 + qw*t2y + cy + tb1;
  out[p*3+2] = x2 + qw*t2z + cz + tb2;
}

// ---------------------------------------------------------------------------
extern "C" void kernel_launch(void* const* d_in, const int* in_sizes, int n_in,
                              void* d_out, int out_size, void* d_ws, size_t ws_size,
                              hipStream_t stream) {
  const float* xyz     = (const float*)d_in[0];
  const float* feature = (const float*)d_in[1];
  const float* centers = (const float*)d_in[2];
  const float* smpl    = (const float*)d_in[3];
  const float* sw      = (const float*)d_in[4];
  const float* bpf     = (const float*)d_in[5];
  const float* w_body  = (const float*)d_in[6];
  const float* b_body  = (const float*)d_in[7];
  const float* w_pos1  = (const float*)d_in[8];
  const float* b_pos1  = (const float*)d_in[9];
  const float* w_pos2  = (const float*)d_in[10];
  const float* b_pos2  = (const float*)d_in[11];
  const float* w_rot   = (const float*)d_in[12];
  const float* b_rot   = (const float*)d_in[13];
  const float* w_trans = (const float*)d_in[14];
  const float* b_trans = (const float*)d_in[15];
  float* out = (float*)d_out;

  float* ws    = (float*)d_ws;
  float* jacc  = ws;              // 80*68 = 5440
  float* jpack = ws + 5440;       // 80*4
  float* qpack = ws + 5760;       // 80*4
  float* tpack = ws + 6080;       // 80*4

  hipMemsetAsync(jacc, 0, 5440 * sizeof(float), stream);
  kA<<<dim3(NTILES), dim3(256), 0, stream>>>(xyz, feature, centers, jacc);
  kB<<<dim3(1), dim3(512), 0, stream>>>(jacc, smpl, sw, bpf,
                                        w_body, b_body, w_pos1, b_pos1,
                                        w_pos2, b_pos2, w_rot, b_rot,
                                        w_trans, b_trans, jpack, qpack, tpack);
  kC<<<dim3(NTILES), dim3(256), 0, stream>>>(xyz, jpack, qpack, tpack, out);
}

// Round 4
// 350.851 us; speedup vs baseline: 1.6563x; 1.6563x over previous
//
#include <hip/hip_runtime.h>
#include <math.h>

#define N_PTS 300000
#define NJ 80          // K joints
#define FDIM 64        // feature dim
#define VN 6890        // smpl verts
#define TILE2 128
#define NT2 ((N_PTS + TILE2 - 1) / TILE2)   // 2344
#define GRID_A 512

typedef __attribute__((ext_vector_type(8))) short short8;
typedef __attribute__((ext_vector_type(4))) float f32x4;

union Frag { uint32_t u[4]; short8 v; };

// exact split: f = hi + lo with hi = truncate-to-bf16(f); pack 8 f32 -> hi/lo frags
__device__ __forceinline__ void split8(const float* r, uint32_t* hw, uint32_t* lw) {
#pragma unroll
  for (int j = 0; j < 4; ++j) {
    uint32_t b0 = __float_as_uint(r[2*j]);
    uint32_t b1 = __float_as_uint(r[2*j+1]);
    hw[j] = (b0 >> 16) | (b1 & 0xFFFF0000u);
    float l0 = r[2*j]   - __uint_as_float(b0 & 0xFFFF0000u);
    float l1 = r[2*j+1] - __uint_as_float(b1 & 0xFFFF0000u);
    lw[j] = (__float_as_uint(l0) >> 16) | (__float_as_uint(l1) & 0xFFFF0000u);
  }
}

// ---------------------------------------------------------------------------
// kP: precompute centers hi/lo bf16 + |c|^2
// ---------------------------------------------------------------------------
__global__ __launch_bounds__(128) void kP(
    const float* __restrict__ centers, ushort* __restrict__ chi,
    ushort* __restrict__ clo, float* __restrict__ cnw)
{
  int k = threadIdx.x;
  if (k >= NJ) return;
  float s = 0.f;
  for (int d = 0; d < FDIM; ++d) {
    float f = centers[k*FDIM + d];
    s += f*f;
    uint32_t b = __float_as_uint(f);
    float lo = f - __uint_as_float(b & 0xFFFF0000u);
    chi[k*FDIM + d] = (ushort)(b >> 16);
    clo[k*FDIM + d] = (ushort)(__float_as_uint(lo) >> 16);
  }
  cnw[k] = s;
}

// ---------------------------------------------------------------------------
// kA: per 128-pt tile: logits = MFMA(F, C^T) -> softmax (in-reg, 16-lane shfl)
//     -> P packed hi|lo to swizzled LDS -> jaccT = MFMA(D^T-from-global, P)
//     GEMM2 accumulators persist across grid-stride tiles; atomics at end.
// ---------------------------------------------------------------------------
__global__ __launch_bounds__(512, 4) void kA(
    const float* __restrict__ xyz, const float* __restrict__ feature,
    const ushort* __restrict__ chi, const ushort* __restrict__ clo,
    const float* __restrict__ cnw, float* __restrict__ jacc)
{
  __shared__ uint32_t sP[NJ][132];     // P packed (hi|lo<<16), pt-swizzled
  __shared__ ushort   sChi[NJ][72];    // centers hi bf16 (pad->2-way banks)
  __shared__ float    sCn[NJ];

  const int tid = threadIdx.x;
  const int w = tid >> 6;        // wave 0..7
  const int l = tid & 63;
  const int i = l & 15;          // lane-in-16
  const int g = l >> 4;          // quarter-group 0..3

  // preload centers-hi + cn
  for (int idx = tid; idx < NJ * 8; idx += 512) {
    int k = idx >> 3, q = idx & 7;
    *(uint4*)&sChi[k][8*q] = *(const uint4*)&chi[k*FDIM + 8*q];
  }
  if (tid < NJ) sCn[tid] = cnw[tid];
  __syncthreads();

  float cnv[5];
#pragma unroll
  for (int nt = 0; nt < 5; ++nt) cnv[nt] = sCn[i + 16*nt];

  f32x4 c2[4];
#pragma unroll
  for (int j = 0; j < 4; ++j) c2[j] = (f32x4){0.f, 0.f, 0.f, 0.f};

  for (int tile = blockIdx.x; tile < NT2; tile += GRID_A) {
    const int base = tile * TILE2;

    // ---------------- GEMM1: logits for pts [base+16w .. +15] --------------
    const int ptA = base + 16*w + i;
    const bool vA = ptA < N_PTS;
    f32x4 acc1[5];
#pragma unroll
    for (int nt = 0; nt < 5; ++nt) acc1[nt] = (f32x4){0.f, 0.f, 0.f, 0.f};

#pragma unroll
    for (int ks = 0; ks < 2; ++ks) {
      float r[8];
      const float* fp = feature + (size_t)ptA * FDIM + 32*ks + 8*g;
#pragma unroll
      for (int e = 0; e < 8; ++e) r[e] = vA ? fp[e] : 0.f;
      Frag ah, al; split8(r, ah.u, al.u);
#pragma unroll
      for (int nt = 0; nt < 5; ++nt) {
        Frag bh, bl;
        *(uint4*)bh.u = *(const uint4*)&sChi[i + 16*nt][32*ks + 8*g];
        *(uint4*)bl.u = *(const uint4*)&clo[(i + 16*nt)*FDIM + 32*ks + 8*g];
        acc1[nt] = __builtin_amdgcn_mfma_f32_16x16x32_bf16(ah.v, bh.v, acc1[nt], 0, 0, 0);
        acc1[nt] = __builtin_amdgcn_mfma_f32_16x16x32_bf16(ah.v, bl.v, acc1[nt], 0, 0, 0);
        acc1[nt] = __builtin_amdgcn_mfma_f32_16x16x32_bf16(al.v, bh.v, acc1[nt], 0, 0, 0);
      }
    }

    // ---------------- softmax over 80 joints, write P to LDS ---------------
    // C layout: row(pt) = 16w + 4g + r, col(joint) = i + 16nt
#pragma unroll
    for (int r = 0; r < 4; ++r) {
      float lg[5];
      float m = -1e30f;
#pragma unroll
      for (int nt = 0; nt < 5; ++nt) {
        lg[nt] = 2.f * acc1[nt][r] - cnv[nt];
        m = fmaxf(m, lg[nt]);
      }
#pragma unroll
      for (int ms = 1; ms < 16; ms <<= 1) m = fmaxf(m, __shfl_xor(m, ms));
      float s = 0.f, ev[5];
#pragma unroll
      for (int nt = 0; nt < 5; ++nt) { ev[nt] = __expf(lg[nt] - m); s += ev[nt]; }
#pragma unroll
      for (int ms = 1; ms < 16; ms <<= 1) s += __shfl_xor(s, ms);
      const float rs = 1.f / s;
      const int ptloc = 16*w + 4*g + r;
      const bool val = (base + ptloc) < N_PTS;
#pragma unroll
      for (int nt = 0; nt < 5; ++nt) {
        float p = ev[nt] * rs;
        uint32_t b = __float_as_uint(p);
        float lo = p - __uint_as_float(b & 0xFFFF0000u);
        uint32_t word = (b >> 16) | ((__float_as_uint(lo) >> 16) << 16);
        word = val ? word : 0u;
        const int row = i + 16*nt;
        sP[row][ptloc ^ ((row & 7) << 3)] = word;
      }
    }
    __syncthreads();   // P complete

    // ---------------- GEMM2: jaccT[col][joint] += D^T * P ------------------
#pragma unroll
    for (int j = 0; j < 4; ++j) {
      const int t = w + 8*j;
      if (t < 25) {
        const int mt = t / 5, nt = t % 5;
#pragma unroll
        for (int ks = 0; ks < 4; ++ks) {
          // A-frag: D[col=16mt+i][pt = base+32ks+8g+e], read transposed from global
          float r[8];
#pragma unroll
          for (int e = 0; e < 8; ++e) {
            const int pt = base + 32*ks + 8*g + e;
            const bool v = pt < N_PTS;
            float x;
            if (mt < 4) {
              x = v ? feature[(size_t)pt * FDIM + 16*mt + i] : 0.f;
            } else {
              if (i < 3)       x = v ? xyz[(size_t)pt * 3 + i] : 0.f;
              else if (i == 3) x = v ? 1.f : 0.f;
              else             x = 0.f;
            }
            r[e] = x;
          }
          Frag ah, al; split8(r, ah.u, al.u);
          // B-frag from swizzled sP
          const int row = i + 16*nt;
          const uint32_t* pp = &sP[row][8 * ((4*ks + g) ^ (row & 7))];
          uint32_t q0[4], q1[4];
          *(uint4*)q0 = *(const uint4*)pp;
          *(uint4*)q1 = *(const uint4*)(pp + 4);
          Frag bh, bl;
          bh.u[0] = (q0[0] & 0xFFFFu) | (q0[1] << 16);
          bh.u[1] = (q0[2] & 0xFFFFu) | (q0[3] << 16);
          bh.u[2] = (q1[0] & 0xFFFFu) | (q1[1] << 16);
          bh.u[3] = (q1[2] & 0xFFFFu) | (q1[3] << 16);
          bl.u[0] = (q0[0] >> 16) | (q0[1] & 0xFFFF0000u);
          bl.u[1] = (q0[2] >> 16) | (q0[3] & 0xFFFF0000u);
          bl.u[2] = (q1[0] >> 16) | (q1[1] & 0xFFFF0000u);
          bl.u[3] = (q1[2] >> 16) | (q1[3] & 0xFFFF0000u);
          c2[j] = __builtin_amdgcn_mfma_f32_16x16x32_bf16(ah.v, bh.v, c2[j], 0, 0, 0);
          c2[j] = __builtin_amdgcn_mfma_f32_16x16x32_bf16(ah.v, bl.v, c2[j], 0, 0, 0);
          c2[j] = __builtin_amdgcn_mfma_f32_16x16x32_bf16(al.v, bh.v, c2[j], 0, 0, 0);
        }
      }
    }
    __syncthreads();   // before next tile overwrites sP
  }

  // epilogue: C layout row(col)=16mt+4g+r, col(joint)=i+16nt
#pragma unroll
  for (int j = 0; j < 4; ++j) {
    const int t = w + 8*j;
    if (t < 25) {
      const int mt = t / 5, nt = t % 5;
      const int joint = i + 16*nt;
#pragma unroll
      for (int r = 0; r < 4; ++r) {
        const int col = 16*mt + 4*g + r;
        if (col < 68) atomicAdd(&jacc[joint*68 + col], c2[j][r]);
      }
    }
  }
}

// ---------------------------------------------------------------------------
// kB: one block (1 wave) per joint: finalize, lo/hi, argmin, full MLP chain
// ---------------------------------------------------------------------------
__global__ __launch_bounds__(64) void kB(
    const float* __restrict__ jacc, const float* __restrict__ smpl,
    const float* __restrict__ sw, const float* __restrict__ bpf,
    const float* __restrict__ w_body, const float* __restrict__ b_body,
    const float* __restrict__ w_pos1, const float* __restrict__ b_pos1,
    const float* __restrict__ w_pos2, const float* __restrict__ b_pos2,
    const float* __restrict__ w_rot,  const float* __restrict__ b_rot,
    const float* __restrict__ w_trans,const float* __restrict__ b_trans,
    float* __restrict__ jpack, float* __restrict__ qpack,
    float* __restrict__ tpack)
{
  const int k = blockIdx.x;
  const int l = threadIdx.x;
  __shared__ float gin[128];   // [body_feat(64) | joint_feat(64)]
  __shared__ float in2[67];    // [xn(3) | g(64)]
  __shared__ float h2[128];
  __shared__ float g2[64];
  __shared__ float q7[8];

  const float cnt = jacc[k*68 + 67] + 1e-6f;
  gin[64 + l] = jacc[k*68 + l] / cnt;          // joint_feat
  const float jx = jacc[k*68 + 64] / cnt;
  const float jy = jacc[k*68 + 65] / cnt;
  const float jz = jacc[k*68 + 66] / cnt;

  // lo/hi over smpl verts (all lanes converge via butterfly)
  float lo0 = 1e30f, lo1 = 1e30f, lo2 = 1e30f;
  float hi0 = -1e30f, hi1 = -1e30f, hi2 = -1e30f;
  // argmin for this joint
  float best = 1e30f; int bi = 0;
  for (int v = l; v < VN; v += 64) {
    float x = smpl[v*3], y = smpl[v*3+1], z = smpl[v*3+2];
    lo0 = fminf(lo0, x); hi0 = fmaxf(hi0, x);
    lo1 = fminf(lo1, y); hi1 = fmaxf(hi1, y);
    lo2 = fminf(lo2, z); hi2 = fmaxf(hi2, z);
    float dx = x - jx, dy = y - jy, dz = z - jz;
    float d = dx*dx + dy*dy + dz*dz;
    if (d < best) { best = d; bi = v; }
  }
#pragma unroll
  for (int m = 1; m < 64; m <<= 1) {
    lo0 = fminf(lo0, __shfl_xor(lo0, m));
    lo1 = fminf(lo1, __shfl_xor(lo1, m));
    lo2 = fminf(lo2, __shfl_xor(lo2, m));
    hi0 = fmaxf(hi0, __shfl_xor(hi0, m));
    hi1 = fmaxf(hi1, __shfl_xor(hi1, m));
    hi2 = fmaxf(hi2, __shfl_xor(hi2, m));
    float d2 = __shfl_xor(best, m); int i2 = __shfl_xor(bi, m);
    if (d2 < best || (d2 == best && i2 < bi)) { best = d2; bi = i2; }
  }

  // body_feat = sw[bi] @ bpf
  {
    float s = 0.f;
    for (int j = 0; j < 24; ++j) s += sw[bi*24 + j] * bpf[j*64 + l];
    gin[l] = s;
  }
  if (l < 3) {
    float lo = (l == 0) ? lo0 : (l == 1) ? lo1 : lo2;
    float hi = (l == 0) ? hi0 : (l == 1) ? hi1 : hi2;
    float jc = (l == 0) ? jx : (l == 1) ? jy : jz;
    in2[l] = 2.f * (jc - lo) / (hi - lo + 1e-6f) - 1.f;
  }
  __syncthreads();

  // layer 1: g = gelu(gin @ w_body + b_body)
  {
    float s = b_body[l];
    for (int t = 0; t < 128; ++t) s += gin[t] * w_body[t*64 + l];
    float u = 0.7978845608028654f * (s + 0.044715f * s * s * s);
    float e = __expf(2.f * u);
    float th = 1.f - 2.f / (e + 1.f);
    in2[3 + l] = 0.5f * s * (1.f + th);
  }
  __syncthreads();

  // layer 2: h = relu(in2 @ w_pos1 + b_pos1)  (128 outs, 2 per lane)
#pragma unroll
  for (int half = 0; half < 2; ++half) {
    const int m = l + 64*half;
    float s = b_pos1[m];
    for (int t = 0; t < 67; ++t) s += in2[t] * w_pos1[t*128 + m];
    h2[m] = fmaxf(s, 0.f);
  }
  __syncthreads();

  // layer 3: g2 = h2 @ w_pos2 + b_pos2
  {
    float s = b_pos2[l];
    for (int t = 0; t < 128; ++t) s += h2[t] * w_pos2[t*64 + l];
    g2[l] = s;
  }
  __syncthreads();

  // layer 4: q and t
  if (l < 4) {
    float s = b_rot[l];
    for (int t = 0; t < 64; ++t) s += g2[t] * w_rot[t*4 + l];
    q7[l] = s;
  } else if (l < 7) {
    const int j = l - 4;
    float s = b_trans[j];
    for (int t = 0; t < 64; ++t) s += g2[t] * w_trans[t*3 + j];
    q7[l] = s;
  }
  __syncthreads();
  if (l == 0) {
    float q0 = q7[0], q1 = q7[1], q2 = q7[2], q3 = q7[3];
    float rn = 1.f / (sqrtf(q0*q0 + q1*q1 + q2*q2 + q3*q3) + 1e-6f);
    *(float4*)&qpack[k*4] = make_float4(q0*rn, q1*rn, q2*rn, q3*rn);
    *(float4*)&tpack[k*4] = make_float4(q7[4], q7[5], q7[6], 0.f);
    *(float4*)&jpack[k*4] = make_float4(jx, jy, jz, jx*jx + jy*jy + jz*jz);
  }
}

// ---------------------------------------------------------------------------
// kC: per-point joint softmax + quaternion blend (joint tables in LDS)
// ---------------------------------------------------------------------------
__global__ __launch_bounds__(256) void kC(
    const float* __restrict__ xyz, const float* __restrict__ jpack,
    const float* __restrict__ qpack, const float* __restrict__ tpack,
    float* __restrict__ out)
{
  __shared__ float4 sj[NJ], sq[NJ], st[NJ];
  const int tid = threadIdx.x;
  if (tid < 80)        sj[tid]       = ((const float4*)jpack)[tid];
  else if (tid < 160)  sq[tid - 80]  = ((const float4*)qpack)[tid - 80];
  else if (tid < 240)  st[tid - 160] = ((const float4*)tpack)[tid - 160];
  __syncthreads();

  const int p = blockIdx.x * 256 + tid;
  if (p >= N_PTS) return;

  float x0 = xyz[p*3], x1 = xyz[p*3+1], x2 = xyz[p*3+2];
  float lv[NJ];
  float m = -1e30f;
#pragma unroll
  for (int k = 0; k < NJ; ++k) {
    float4 j = sj[k];
    lv[k] = (2.f*(x0*j.x + x1*j.y + x2*j.z) - j.w) * 10.0f;  // 1/SIGMA
    m = fmaxf(m, lv[k]);
  }
  float s = 0.f;
  float qb0=0,qb1=0,qb2=0,qb3=0, tb0=0,tb1=0,tb2=0;
#pragma unroll
  for (int k = 0; k < NJ; ++k) {
    float e = __expf(lv[k] - m);
    s += e;
    float4 q = sq[k];
    float4 t = st[k];
    qb0 += e*q.x; qb1 += e*q.y; qb2 += e*q.z; qb3 += e*q.w;
    tb0 += e*t.x; tb1 += e*t.y; tb2 += e*t.z;
  }
  float rs = 1.f / s;
  qb0*=rs; qb1*=rs; qb2*=rs; qb3*=rs; tb0*=rs; tb1*=rs; tb2*=rs;
  float nrm = sqrtf(qb0*qb0+qb1*qb1+qb2*qb2+qb3*qb3) + 1e-6f;
  float rn = 1.f / nrm;
  float qw = qb0*rn, qx = qb1*rn, qy = qb2*rn, qz = qb3*rn;
  float t2x = 2.f*(qy*x2 - qz*x1);
  float t2y = 2.f*(qz*x0 - qx*x2);
  float t2z = 2.f*(qx*x1 - qy*x0);
  float cx = qy*t2z - qz*t2y;
  float cy = qz*t2x - qx*t2z;
  float cz = qx*t2y - qy*t2x;
  out[p*3]   = x0 + qw*t2x + cx + tb0;
  out[p*3+1] = x1 + qw*t2y + cy + tb1;
  out[p*3+2] = x2 + qw*t2z + cz + tb2;
}

// ---------------------------------------------------------------------------
extern "C" void kernel_launch(void* const* d_in, const int* in_sizes, int n_in,
                              void* d_out, int out_size, void* d_ws, size_t ws_size,
                              hipStream_t stream) {
  const float* xyz     = (const float*)d_in[0];
  const float* feature = (const float*)d_in[1];
  const float* centers = (const float*)d_in[2];
  const float* smpl    = (const float*)d_in[3];
  const float* sw      = (const float*)d_in[4];
  const float* bpf     = (const float*)d_in[5];
  const float* w_body  = (const float*)d_in[6];
  const float* b_body  = (const float*)d_in[7];
  const float* w_pos1  = (const float*)d_in[8];
  const float* b_pos1  = (const float*)d_in[9];
  const float* w_pos2  = (const float*)d_in[10];
  const float* b_pos2  = (const float*)d_in[11];
  const float* w_rot   = (const float*)d_in[12];
  const float* b_rot   = (const float*)d_in[13];
  const float* w_trans = (const float*)d_in[14];
  const float* b_trans = (const float*)d_in[15];
  float* out = (float*)d_out;

  float* ws    = (float*)d_ws;
  float* jacc  = ws;                  // 80*68 = 5440 f32
  float* jpack = ws + 5440;           // 80*4
  float* qpack = ws + 5760;           // 80*4
  float* tpack = ws + 6080;           // 80*4
  float* cnw   = ws + 6400;           // 80
  ushort* chi  = (ushort*)(ws + 6480);          // 80*64 u16
  ushort* clo  = (ushort*)(ws + 6480 + 2560);   // 80*64 u16

  hipMemsetAsync(jacc, 0, 5440 * sizeof(float), stream);
  kP<<<dim3(1), dim3(128), 0, stream>>>(centers, chi, clo, cnw);
  kA<<<dim3(GRID_A), dim3(512), 0, stream>>>(xyz, feature, chi, clo, cnw, jacc);
  kB<<<dim3(NJ), dim3(64), 0, stream>>>(jacc, smpl, sw, bpf,
                                        w_body, b_body, w_pos1, b_pos1,
                                        w_pos2, b_pos2, w_rot, b_rot,
                                        w_trans, b_trans, jpack, qpack, tpack);
  kC<<<dim3((N_PTS + 255) / 256), dim3(256), 0, stream>>>(xyz, jpack, qpack, tpack, out);
}

// Round 5
// 320.584 us; speedup vs baseline: 1.8127x; 1.0944x over previous
//
#include <hip/hip_runtime.h>
#include <math.h>

#define N_PTS 300000
#define NJ 80          // K joints
#define FDIM 64        // feature dim
#define VN 6890        // smpl verts
#define NCH 4688       // ceil(300000/64)
#define GRID_A 768

typedef __attribute__((ext_vector_type(8))) short short8;
typedef __attribute__((ext_vector_type(4))) float f32x4;

union Frag { uint32_t u[4]; short8 v; };

// pack f32 -> u32: bf16-hi (truncated) in low half, bf16-lo (residual) in high half
__device__ __forceinline__ uint32_t pack1(float f) {
  uint32_t b = __float_as_uint(f);
  float lo = f - __uint_as_float(b & 0xFFFF0000u);
  return (b >> 16) | ((__float_as_uint(lo) >> 16) << 16);
}

// 8 packed words -> hi-frag / lo-frag (bf16x8 each)
__device__ __forceinline__ void unpack8(const uint32_t* W, uint32_t* hw, uint32_t* lw) {
#pragma unroll
  for (int j = 0; j < 4; ++j) {
    hw[j] = (W[2*j] & 0xFFFFu) | (W[2*j+1] << 16);
    lw[j] = (W[2*j] >> 16) | (W[2*j+1] & 0xFFFF0000u);
  }
}

// ---------------------------------------------------------------------------
// kA: fused softmax(-sqdist(feature,centers)) + jacc[joint][col] += P^T * D
//     cols: 0..63 feature, 64..66 xyz, 67 = valid-flag (cnt)
// Per 64-pt chunk:
//   GEMM1: A = feature rows from GLOBAL (coalesced), B = centers (registers),
//          3x bf16 MFMA (hi*hi + hi*lo + lo*hi). Lanes then write the tile
//          packed & TRANSPOSED to sFT[col][pt] (b32 scatter, cheap).
//   softmax: in-register over 5 frags + 16-lane shfl reduce -> sP[joint][pt].
//   GEMM2: A from sFT (contig b128), B from sP (contig b128), 25 16x16 tiles
//          over 4 waves, accumulators persist across chunks; atomics at end.
// ---------------------------------------------------------------------------
__global__ __launch_bounds__(256) void kA(
    const float* __restrict__ xyz, const float* __restrict__ feature,
    const float* __restrict__ centers, float* __restrict__ jacc)
{
  __shared__ uint32_t sFT[80][76];   // packed data, [col][pt]; rows 68..79 zero
  __shared__ uint32_t sP[80][84];    // packed P, [joint][pt]

  const int tid = threadIdx.x;
  const int w = tid >> 6;
  const int l = tid & 63;
  const int i = l & 15;
  const int g = l >> 4;

  // zero pad rows 68..79 (read by the mt=4 tile, masked at epilogue)
  for (int z = tid; z < 12 * 76; z += 256) sFT[68 + z / 76][z % 76] = 0;

  // ---- centers -> register B-frags (hi/lo) + |c|^2 ----
  Frag bh[5][2], bl[5][2];
  float cnv[5];
#pragma unroll
  for (int nt = 0; nt < 5; ++nt) {
    const float* cp = centers + (i + 16*nt) * FDIM + 8*g;
    float r0[8], r1[8];
    float s = 0.f;
#pragma unroll
    for (int e = 0; e < 8; ++e) {
      r0[e] = cp[e]; r1[e] = cp[32 + e];
      s += r0[e]*r0[e] + r1[e]*r1[e];
    }
    uint32_t w0[8], w1[8];
#pragma unroll
    for (int e = 0; e < 8; ++e) { w0[e] = pack1(r0[e]); w1[e] = pack1(r1[e]); }
    unpack8(w0, bh[nt][0].u, bl[nt][0].u);
    unpack8(w1, bh[nt][1].u, bl[nt][1].u);
    s += __shfl_xor(s, 16);
    s += __shfl_xor(s, 32);
    cnv[nt] = s;
  }

  f32x4 c2[7];
#pragma unroll
  for (int u = 0; u < 7; ++u) c2[u] = (f32x4){0.f, 0.f, 0.f, 0.f};

  __syncthreads();

  for (int chunk = blockIdx.x; chunk < NCH; chunk += GRID_A) {
    const int base = chunk * 64;

    // ---------------- GEMM1 + transpose-stage ----------------
    const int ptA = base + 16*w + i;
    const bool vA = ptA < N_PTS;
    f32x4 acc1[5];
#pragma unroll
    for (int nt = 0; nt < 5; ++nt) acc1[nt] = (f32x4){0.f, 0.f, 0.f, 0.f};

#pragma unroll
    for (int ks = 0; ks < 2; ++ks) {
      float r[8];
      const float* fp = feature + (size_t)ptA * FDIM + 32*ks + 8*g;
#pragma unroll
      for (int e = 0; e < 8; ++e) r[e] = vA ? fp[e] : 0.f;
      uint32_t pw[8];
#pragma unroll
      for (int e = 0; e < 8; ++e) pw[e] = pack1(r[e]);
      // transposed stage: sFT[col][pt]
#pragma unroll
      for (int e = 0; e < 8; ++e) sFT[32*ks + 8*g + e][16*w + i] = pw[e];
      Frag ah, al;
      unpack8(pw, ah.u, al.u);
#pragma unroll
      for (int nt = 0; nt < 5; ++nt) {
        acc1[nt] = __builtin_amdgcn_mfma_f32_16x16x32_bf16(ah.v, bh[nt][ks].v, acc1[nt], 0, 0, 0);
        acc1[nt] = __builtin_amdgcn_mfma_f32_16x16x32_bf16(ah.v, bl[nt][ks].v, acc1[nt], 0, 0, 0);
        acc1[nt] = __builtin_amdgcn_mfma_f32_16x16x32_bf16(al.v, bh[nt][ks].v, acc1[nt], 0, 0, 0);
      }
    }

    // xyz + ones row (cols 64..67), wave 0 only
    if (tid < 64) {
      const int pt = base + tid;
      const bool v = pt < N_PTS;
      float x = v ? xyz[(size_t)pt*3 + 0] : 0.f;
      float y = v ? xyz[(size_t)pt*3 + 1] : 0.f;
      float z = v ? xyz[(size_t)pt*3 + 2] : 0.f;
      sFT[64][tid] = pack1(x);
      sFT[65][tid] = pack1(y);
      sFT[66][tid] = pack1(z);
      sFT[67][tid] = v ? pack1(1.f) : 0u;
    }

    // ---------------- softmax -> sP[joint][pt] ----------------
#pragma unroll
    for (int r = 0; r < 4; ++r) {
      float lg[5];
      float m = -1e30f;
#pragma unroll
      for (int nt = 0; nt < 5; ++nt) {
        lg[nt] = 2.f * acc1[nt][r] - cnv[nt];
        m = fmaxf(m, lg[nt]);
      }
#pragma unroll
      for (int ms = 1; ms < 16; ms <<= 1) m = fmaxf(m, __shfl_xor(m, ms));
      float ev[5], s = 0.f;
#pragma unroll
      for (int nt = 0; nt < 5; ++nt) { ev[nt] = __expf(lg[nt] - m); s += ev[nt]; }
#pragma unroll
      for (int ms = 1; ms < 16; ms <<= 1) s += __shfl_xor(s, ms);
      const float rs = 1.f / s;
      const int slot = 16*w + 4*g + r;
      const bool val = (base + slot) < N_PTS;
#pragma unroll
      for (int nt = 0; nt < 5; ++nt) {
        uint32_t word = val ? pack1(ev[nt] * rs) : 0u;
        sP[i + 16*nt][slot] = word;
      }
    }
    __syncthreads();   // sFT + sP complete

    // ---------------- GEMM2: 25 tiles over 4 waves ----------------
#pragma unroll
    for (int u = 0; u < 7; ++u) {
      const int t = 4*u + w;
      if (t < 25) {
        const int mt = t / 5, nt5 = t % 5;
#pragma unroll
        for (int ks = 0; ks < 2; ++ks) {
          uint32_t W[8];
          *(uint4*)&W[0] = *(const uint4*)&sFT[16*mt + i][32*ks + 8*g];
          *(uint4*)&W[4] = *(const uint4*)&sFT[16*mt + i][32*ks + 8*g + 4];
          Frag ah, al;
          unpack8(W, ah.u, al.u);
          uint32_t Q[8];
          *(uint4*)&Q[0] = *(const uint4*)&sP[i + 16*nt5][32*ks + 8*g];
          *(uint4*)&Q[4] = *(const uint4*)&sP[i + 16*nt5][32*ks + 8*g + 4];
          Frag ph, pl;
          unpack8(Q, ph.u, pl.u);
          c2[u] = __builtin_amdgcn_mfma_f32_16x16x32_bf16(ah.v, ph.v, c2[u], 0, 0, 0);
          c2[u] = __builtin_amdgcn_mfma_f32_16x16x32_bf16(ah.v, pl.v, c2[u], 0, 0, 0);
          c2[u] = __builtin_amdgcn_mfma_f32_16x16x32_bf16(al.v, ph.v, c2[u], 0, 0, 0);
        }
      }
    }
    __syncthreads();   // before next chunk overwrites sFT/sP
  }

  // epilogue: C row = col-c = 16mt+4g+r, C col = joint = i+16nt5
#pragma unroll
  for (int u = 0; u < 7; ++u) {
    const int t = 4*u + w;
    if (t < 25) {
      const int mt = t / 5, nt5 = t % 5;
      const int joint = i + 16*nt5;
#pragma unroll
      for (int r = 0; r < 4; ++r) {
        const int c = 16*mt + 4*g + r;
        if (c < 68) atomicAdd(&jacc[joint * 68 + c], c2[u][r]);
      }
    }
  }
}

// ---------------------------------------------------------------------------
// kB: one block (1 wave) per joint: finalize, lo/hi, argmin, full MLP chain
// ---------------------------------------------------------------------------
__global__ __launch_bounds__(64) void kB(
    const float* __restrict__ jacc, const float* __restrict__ smpl,
    const float* __restrict__ sw, const float* __restrict__ bpf,
    const float* __restrict__ w_body, const float* __restrict__ b_body,
    const float* __restrict__ w_pos1, const float* __restrict__ b_pos1,
    const float* __restrict__ w_pos2, const float* __restrict__ b_pos2,
    const float* __restrict__ w_rot,  const float* __restrict__ b_rot,
    const float* __restrict__ w_trans,const float* __restrict__ b_trans,
    float* __restrict__ jpack, float* __restrict__ qpack,
    float* __restrict__ tpack)
{
  const int k = blockIdx.x;
  const int l = threadIdx.x;
  __shared__ float gin[128];   // [body_feat(64) | joint_feat(64)]
  __shared__ float in2[67];    // [xn(3) | g(64)]
  __shared__ float h2[128];
  __shared__ float g2[64];
  __shared__ float q7[8];

  const float cnt = jacc[k*68 + 67] + 1e-6f;
  gin[64 + l] = jacc[k*68 + l] / cnt;          // joint_feat
  const float jx = jacc[k*68 + 64] / cnt;
  const float jy = jacc[k*68 + 65] / cnt;
  const float jz = jacc[k*68 + 66] / cnt;

  float lo0 = 1e30f, lo1 = 1e30f, lo2 = 1e30f;
  float hi0 = -1e30f, hi1 = -1e30f, hi2 = -1e30f;
  float best = 1e30f; int bi = 0;
  for (int v = l; v < VN; v += 64) {
    float x = smpl[v*3], y = smpl[v*3+1], z = smpl[v*3+2];
    lo0 = fminf(lo0, x); hi0 = fmaxf(hi0, x);
    lo1 = fminf(lo1, y); hi1 = fmaxf(hi1, y);
    lo2 = fminf(lo2, z); hi2 = fmaxf(hi2, z);
    float dx = x - jx, dy = y - jy, dz = z - jz;
    float d = dx*dx + dy*dy + dz*dz;
    if (d < best) { best = d; bi = v; }
  }
#pragma unroll
  for (int m = 1; m < 64; m <<= 1) {
    lo0 = fminf(lo0, __shfl_xor(lo0, m));
    lo1 = fminf(lo1, __shfl_xor(lo1, m));
    lo2 = fminf(lo2, __shfl_xor(lo2, m));
    hi0 = fmaxf(hi0, __shfl_xor(hi0, m));
    hi1 = fmaxf(hi1, __shfl_xor(hi1, m));
    hi2 = fmaxf(hi2, __shfl_xor(hi2, m));
    float d2 = __shfl_xor(best, m); int i2 = __shfl_xor(bi, m);
    if (d2 < best || (d2 == best && i2 < bi)) { best = d2; bi = i2; }
  }

  {
    float s = 0.f;
    for (int j = 0; j < 24; ++j) s += sw[bi*24 + j] * bpf[j*64 + l];
    gin[l] = s;
  }
  if (l < 3) {
    float lo = (l == 0) ? lo0 : (l == 1) ? lo1 : lo2;
    float hi = (l == 0) ? hi0 : (l == 1) ? hi1 : hi2;
    float jc = (l == 0) ? jx : (l == 1) ? jy : jz;
    in2[l] = 2.f * (jc - lo) / (hi - lo + 1e-6f) - 1.f;
  }
  __syncthreads();

  {
    float s = b_body[l];
    for (int t = 0; t < 128; ++t) s += gin[t] * w_body[t*64 + l];
    float u = 0.7978845608028654f * (s + 0.044715f * s * s * s);
    float e = __expf(2.f * u);
    float th = 1.f - 2.f / (e + 1.f);
    in2[3 + l] = 0.5f * s * (1.f + th);
  }
  __syncthreads();

#pragma unroll
  for (int half = 0; half < 2; ++half) {
    const int m = l + 64*half;
    float s = b_pos1[m];
    for (int t = 0; t < 67; ++t) s += in2[t] * w_pos1[t*128 + m];
    h2[m] = fmaxf(s, 0.f);
  }
  __syncthreads();

  {
    float s = b_pos2[l];
    for (int t = 0; t < 128; ++t) s += h2[t] * w_pos2[t*64 + l];
    g2[l] = s;
  }
  __syncthreads();

  if (l < 4) {
    float s = b_rot[l];
    for (int t = 0; t < 64; ++t) s += g2[t] * w_rot[t*4 + l];
    q7[l] = s;
  } else if (l < 7) {
    const int j = l - 4;
    float s = b_trans[j];
    for (int t = 0; t < 64; ++t) s += g2[t] * w_trans[t*3 + j];
    q7[l] = s;
  }
  __syncthreads();
  if (l == 0) {
    float q0 = q7[0], q1 = q7[1], q2 = q7[2], q3 = q7[3];
    float rn = 1.f / (sqrtf(q0*q0 + q1*q1 + q2*q2 + q3*q3) + 1e-6f);
    *(float4*)&qpack[k*4] = make_float4(q0*rn, q1*rn, q2*rn, q3*rn);
    *(float4*)&tpack[k*4] = make_float4(q7[4], q7[5], q7[6], 0.f);
    *(float4*)&jpack[k*4] = make_float4(jx, jy, jz, jx*jx + jy*jy + jz*jz);
  }
}

// ---------------------------------------------------------------------------
// kC: per-point joint softmax + quaternion blend (joint tables in LDS)
// ---------------------------------------------------------------------------
__global__ __launch_bounds__(256) void kC(
    const float* __restrict__ xyz, const float* __restrict__ jpack,
    const float* __restrict__ qpack, const float* __restrict__ tpack,
    float* __restrict__ out)
{
  __shared__ float4 sj[NJ], sq[NJ], st[NJ];
  const int tid = threadIdx.x;
  if (tid < 80)        sj[tid]       = ((const float4*)jpack)[tid];
  else if (tid < 160)  sq[tid - 80]  = ((const float4*)qpack)[tid - 80];
  else if (tid < 240)  st[tid - 160] = ((const float4*)tpack)[tid - 160];
  __syncthreads();

  const int p = blockIdx.x * 256 + tid;
  if (p >= N_PTS) return;

  float x0 = xyz[p*3], x1 = xyz[p*3+1], x2 = xyz[p*3+2];
  float lv[NJ];
  float m = -1e30f;
#pragma unroll
  for (int k = 0; k < NJ; ++k) {
    float4 j = sj[k];
    lv[k] = (2.f*(x0*j.x + x1*j.y + x2*j.z) - j.w) * 10.0f;  // 1/SIGMA
    m = fmaxf(m, lv[k]);
  }
  float s = 0.f;
  float qb0=0,qb1=0,qb2=0,qb3=0, tb0=0,tb1=0,tb2=0;
#pragma unroll
  for (int k = 0; k < NJ; ++k) {
    float e = __expf(lv[k] - m);
    s += e;
    float4 q = sq[k];
    float4 t = st[k];
    qb0 += e*q.x; qb1 += e*q.y; qb2 += e*q.z; qb3 += e*q.w;
    tb0 += e*t.x; tb1 += e*t.y; tb2 += e*t.z;
  }
  float rs = 1.f / s;
  qb0*=rs; qb1*=rs; qb2*=rs; qb3*=rs; tb0*=rs; tb1*=rs; tb2*=rs;
  float nrm = sqrtf(qb0*qb0+qb1*qb1+qb2*qb2+qb3*qb3) + 1e-6f;
  float rn = 1.f / nrm;
  float qw = qb0*rn, qx = qb1*rn, qy = qb2*rn, qz = qb3*rn;
  float t2x = 2.f*(qy*x2 - qz*x1);
  float t2y = 2.f*(qz*x0 - qx*x2);
  float t2z = 2.f*(qx*x1 - qy*x0);
  float cx = qy*t2z - qz*t2y;
  float cy = qz*t2x - qx*t2z;
  float cz = qx*t2y - qy*t2x;
  out[p*3]   = x0 + qw*t2x + cx + tb0;
  out[p*3+1] = x1 + qw*t2y + cy + tb1;
  out[p*3+2] = x2 + qw*t2z + cz + tb2;
}

// ---------------------------------------------------------------------------
extern "C" void kernel_launch(void* const* d_in, const int* in_sizes, int n_in,
                              void* d_out, int out_size, void* d_ws, size_t ws_size,
                              hipStream_t stream) {
  const float* xyz     = (const float*)d_in[0];
  const float* feature = (const float*)d_in[1];
  const float* centers = (const float*)d_in[2];
  const float* smpl    = (const float*)d_in[3];
  const float* sw      = (const float*)d_in[4];
  const float* bpf     = (const float*)d_in[5];
  const float* w_body  = (const float*)d_in[6];
  const float* b_body  = (const float*)d_in[7];
  const float* w_pos1  = (const float*)d_in[8];
  const float* b_pos1  = (const float*)d_in[9];
  const float* w_pos2  = (const float*)d_in[10];
  const float* b_pos2  = (const float*)d_in[11];
  const float* w_rot   = (const float*)d_in[12];
  const float* b_rot   = (const float*)d_in[13];
  const float* w_trans = (const float*)d_in[14];
  const float* b_trans = (const float*)d_in[15];
  float* out = (float*)d_out;

  float* ws    = (float*)d_ws;
  float* jacc  = ws;                  // 80*68 = 5440 f32
  float* jpack = ws + 5440;           // 80*4
  float* qpack = ws + 5760;           // 80*4
  float* tpack = ws + 6080;           // 80*4

  hipMemsetAsync(jacc, 0, 5440 * sizeof(float), stream);
  kA<<<dim3(GRID_A), dim3(256), 0, stream>>>(xyz, feature, centers, jacc);
  kB<<<dim3(NJ), dim3(64), 0, stream>>>(jacc, smpl, sw, bpf,
                                        w_body, b_body, w_pos1, b_pos1,
                                        w_pos2, b_pos2, w_rot, b_rot,
                                        w_trans, b_trans, jpack, qpack, tpack);
  kC<<<dim3((N_PTS + 255) / 256), dim3(256), 0, stream>>>(xyz, jpack, qpack, tpack, out);
}

// Round 6
// 157.801 us; speedup vs baseline: 3.6826x; 2.0316x over previous
//
#include <hip/hip_runtime.h>
#include <math.h>

#define N_PTS 300000
#define NJ 80          // K joints
#define FDIM 64        // feature dim
#define VN 6890        // smpl verts
#define ITER_PTS 128
#define NITER ((N_PTS + ITER_PTS - 1) / ITER_PTS)   // 2344
#define GRID_A 768
#define RSLICE 16      // kR b-slices

typedef __attribute__((ext_vector_type(8))) short short8;
typedef __attribute__((ext_vector_type(4))) float f32x4;

union Frag { uint32_t u[4]; short8 v; };

// pack f32 -> u32: bf16-hi (truncated) low half, bf16-lo (residual) high half
__device__ __forceinline__ uint32_t pack1(float f) {
  uint32_t b = __float_as_uint(f);
  float lo = f - __uint_as_float(b & 0xFFFF0000u);
  return (b >> 16) | ((__float_as_uint(lo) >> 16) << 16);
}
__device__ __forceinline__ void unpack8(const uint32_t* W, uint32_t* hw, uint32_t* lw) {
#pragma unroll
  for (int j = 0; j < 4; ++j) {
    hw[j] = (W[2*j] & 0xFFFFu) | (W[2*j+1] << 16);
    lw[j] = (W[2*j] >> 16) | (W[2*j+1] & 0xFFFF0000u);
  }
}

// ---------------------------------------------------------------------------
// kA: per 128-pt iter (8 waves):
//   GEMM1 (per wave, 16 pts): A = feature from global (coalesced, packed
//     hi/lo), B = centers from LDS sC (packed hi|lo, padded rows); 3-term
//     bf16 MFMA -> logits; in-register softmax (16-lane shfl) ->
//     sP[joint][pt] bf16-hi, XOR-swizzled.
//   barrier.
//   GEMM2 (waves 0..4, wave w = mt-row w): A = D^T read from global
//     (lane-coalesced 64B segs, L1/L2-hot from GEMM1), B = sP via swizzled
//     ds_read_b128; 1 bf16 MFMA per (nt,kk); acc persists across iters.
//   barrier.
// Epilogue: per-block partial tile store to ws (or atomics fallback).
// ---------------------------------------------------------------------------
__global__ __launch_bounds__(512, 6) void kA(
    const float* __restrict__ xyz, const float* __restrict__ feature,
    const float* __restrict__ centers, float* __restrict__ jacc,
    float* __restrict__ part)
{
  __shared__ uint32_t sC[NJ][68];   // centers packed hi|lo, pad 68 -> 2-way banks
  __shared__ float    sCn[NJ];      // |c_k|^2 (full f32)
  __shared__ ushort   sP[NJ][136];  // P bf16-hi, [joint][pt^swz], pad 136

  const int tid = threadIdx.x;
  const int w = tid >> 6;          // wave 0..7
  const int l = tid & 63;
  const int i = l & 15;
  const int g = l >> 4;

  // ---- init sC / sCn ----
  for (int idx = tid; idx < NJ * 16; idx += 512) {
    int k = idx >> 4, q = idx & 15;
    float4 v = ((const float4*)centers)[k * 16 + q];
    sC[k][4*q+0] = pack1(v.x); sC[k][4*q+1] = pack1(v.y);
    sC[k][4*q+2] = pack1(v.z); sC[k][4*q+3] = pack1(v.w);
  }
  if (tid < NJ) {
    float s = 0.f;
    const float* c = centers + tid * FDIM;
    for (int d = 0; d < FDIM; ++d) s += c[d] * c[d];
    sCn[tid] = s;
  }
  __syncthreads();

  float cnv[5];
#pragma unroll
  for (int nt = 0; nt < 5; ++nt) cnv[nt] = sCn[i + 16*nt];

  f32x4 acc2[5];
#pragma unroll
  for (int nt = 0; nt < 5; ++nt) acc2[nt] = (f32x4){0.f, 0.f, 0.f, 0.f};

  for (int it = blockIdx.x; it < NITER; it += GRID_A) {
    const int base = it * ITER_PTS;

    // ---------------- GEMM1: 16 pts per wave ----------------
    const int ptA = base + 16*w + i;
    const int ptAc = ptA < N_PTS ? ptA : N_PTS - 1;
    const bool vA = ptA < N_PTS;
    f32x4 acc1[5];
#pragma unroll
    for (int nt = 0; nt < 5; ++nt) acc1[nt] = (f32x4){0.f, 0.f, 0.f, 0.f};

#pragma unroll
    for (int ks = 0; ks < 2; ++ks) {
      const float* fp = feature + (size_t)ptAc * FDIM + 32*ks + 8*g;
      uint32_t pw[8];
#pragma unroll
      for (int e = 0; e < 8; ++e) pw[e] = vA ? pack1(fp[e]) : 0u;
      Frag ah, al; unpack8(pw, ah.u, al.u);
#pragma unroll
      for (int nt = 0; nt < 5; ++nt) {
        uint32_t W[8];
        *(uint4*)&W[0] = *(const uint4*)&sC[i + 16*nt][32*ks + 8*g];
        *(uint4*)&W[4] = *(const uint4*)&sC[i + 16*nt][32*ks + 8*g + 4];
        Frag bh, bl; unpack8(W, bh.u, bl.u);
        acc1[nt] = __builtin_amdgcn_mfma_f32_16x16x32_bf16(ah.v, bh.v, acc1[nt], 0, 0, 0);
        acc1[nt] = __builtin_amdgcn_mfma_f32_16x16x32_bf16(ah.v, bl.v, acc1[nt], 0, 0, 0);
        acc1[nt] = __builtin_amdgcn_mfma_f32_16x16x32_bf16(al.v, bh.v, acc1[nt], 0, 0, 0);
      }
    }

    // ---------------- softmax -> sP (bf16-hi, swizzled) ----------------
#pragma unroll
    for (int r = 0; r < 4; ++r) {
      float lg[5]; float m = -1e30f;
#pragma unroll
      for (int nt = 0; nt < 5; ++nt) {
        lg[nt] = 2.f * acc1[nt][r] - cnv[nt];
        m = fmaxf(m, lg[nt]);
      }
#pragma unroll
      for (int ms = 1; ms < 16; ms <<= 1) m = fmaxf(m, __shfl_xor(m, ms));
      float ev[5], s = 0.f;
#pragma unroll
      for (int nt = 0; nt < 5; ++nt) { ev[nt] = __expf(lg[nt] - m); s += ev[nt]; }
#pragma unroll
      for (int ms = 1; ms < 16; ms <<= 1) s += __shfl_xor(s, ms);
      const float rs = 1.f / s;
      const int slot = 16*w + 4*g + r;          // C row = pt
      const bool val = (base + slot) < N_PTS;
#pragma unroll
      for (int nt = 0; nt < 5; ++nt) {
        const int row = i + 16*nt;              // C col = joint
        ushort h = val ? (ushort)(__float_as_uint(ev[nt] * rs) >> 16) : (ushort)0;
        sP[row][slot ^ ((row & 7) << 3)] = h;
      }
    }
    __syncthreads();   // sP complete

    // ---------------- GEMM2: waves 0..4, mt = w ----------------
    if (w < 5) {
#pragma unroll
      for (int kk = 0; kk < 4; ++kk) {
        Frag af;
#pragma unroll
        for (int p2 = 0; p2 < 4; ++p2) {
          float x0, x1;
#pragma unroll
          for (int h = 0; h < 2; ++h) {
            const int e = 2*p2 + h;
            const int pt = base + 32*kk + 8*g + e;
            const int ptc = pt < N_PTS ? pt : N_PTS - 1;
            float x;
            if (w < 4) x = feature[(size_t)ptc * FDIM + 16*w + i];
            else       x = (i < 3) ? xyz[(size_t)ptc * 3 + i] : (i == 3 ? 1.f : 0.f);
            if (h == 0) x0 = x; else x1 = x;
          }
          af.u[p2] = (__float_as_uint(x0) >> 16) | (__float_as_uint(x1) & 0xFFFF0000u);
        }
#pragma unroll
        for (int nt = 0; nt < 5; ++nt) {
          const int row = i + 16*nt;
          const int start = (32*kk + 8*g) ^ ((row & 7) << 3);
          Frag bf;
          *(uint4*)bf.u = *(const uint4*)&sP[row][start];
          acc2[nt] = __builtin_amdgcn_mfma_f32_16x16x32_bf16(af.v, bf.v, acc2[nt], 0, 0, 0);
        }
      }
    }
    __syncthreads();   // before next iter overwrites sP
  }

  // ---- epilogue: per-block partials (or atomic fallback) ----
  if (w < 5) {
#pragma unroll
    for (int nt = 0; nt < 5; ++nt) {
      const int joint = i + 16*nt;
#pragma unroll
      for (int r = 0; r < 4; ++r) {
        const int c = 16*w + 4*g + r;
        if (c < 68) {
          if (part) part[(size_t)blockIdx.x * 5440 + joint * 68 + c] = acc2[nt][r];
          else atomicAdd(&jacc[joint * 68 + c], acc2[nt][r]);
        }
      }
    }
  }
}

// ---------------------------------------------------------------------------
// kR: jacc[t] += sum over partials (sliced for parallelism)
// ---------------------------------------------------------------------------
__global__ __launch_bounds__(256) void kR(const float* __restrict__ part,
                                          float* __restrict__ jacc)
{
  const int bx = blockIdx.x;
  const int cg = bx % 22, sl = bx / 22;
  const int t = cg * 256 + threadIdx.x;
  if (t >= 5440) return;
  const int b0 = sl * (GRID_A / RSLICE), b1 = b0 + GRID_A / RSLICE;
  float s0 = 0.f, s1 = 0.f, s2 = 0.f, s3 = 0.f;
  for (int b = b0; b < b1; b += 4) {
    s0 += part[(size_t)(b+0) * 5440 + t];
    s1 += part[(size_t)(b+1) * 5440 + t];
    s2 += part[(size_t)(b+2) * 5440 + t];
    s3 += part[(size_t)(b+3) * 5440 + t];
  }
  atomicAdd(&jacc[t], (s0 + s1) + (s2 + s3));
}

// ---------------------------------------------------------------------------
// kB: one block (1 wave) per joint: finalize, lo/hi, argmin, full MLP chain
// ---------------------------------------------------------------------------
__global__ __launch_bounds__(64) void kB(
    const float* __restrict__ jacc, const float* __restrict__ smpl,
    const float* __restrict__ sw, const float* __restrict__ bpf,
    const float* __restrict__ w_body, const float* __restrict__ b_body,
    const float* __restrict__ w_pos1, const float* __restrict__ b_pos1,
    const float* __restrict__ w_pos2, const float* __restrict__ b_pos2,
    const float* __restrict__ w_rot,  const float* __restrict__ b_rot,
    const float* __restrict__ w_trans,const float* __restrict__ b_trans,
    float* __restrict__ jpack, float* __restrict__ qpack,
    float* __restrict__ tpack)
{
  const int k = blockIdx.x;
  const int l = threadIdx.x;
  __shared__ float gin[128];
  __shared__ float in2[67];
  __shared__ float h2[128];
  __shared__ float g2[64];
  __shared__ float q7[8];

  const float cnt = jacc[k*68 + 67] + 1e-6f;
  gin[64 + l] = jacc[k*68 + l] / cnt;
  const float jx = jacc[k*68 + 64] / cnt;
  const float jy = jacc[k*68 + 65] / cnt;
  const float jz = jacc[k*68 + 66] / cnt;

  float lo0 = 1e30f, lo1 = 1e30f, lo2 = 1e30f;
  float hi0 = -1e30f, hi1 = -1e30f, hi2 = -1e30f;
  float best = 1e30f; int bi = 0;
  for (int v = l; v < VN; v += 64) {
    float x = smpl[v*3], y = smpl[v*3+1], z = smpl[v*3+2];
    lo0 = fminf(lo0, x); hi0 = fmaxf(hi0, x);
    lo1 = fminf(lo1, y); hi1 = fmaxf(hi1, y);
    lo2 = fminf(lo2, z); hi2 = fmaxf(hi2, z);
    float dx = x - jx, dy = y - jy, dz = z - jz;
    float d = dx*dx + dy*dy + dz*dz;
    if (d < best) { best = d; bi = v; }
  }
#pragma unroll
  for (int m = 1; m < 64; m <<= 1) {
    lo0 = fminf(lo0, __shfl_xor(lo0, m));
    lo1 = fminf(lo1, __shfl_xor(lo1, m));
    lo2 = fminf(lo2, __shfl_xor(lo2, m));
    hi0 = fmaxf(hi0, __shfl_xor(hi0, m));
    hi1 = fmaxf(hi1, __shfl_xor(hi1, m));
    hi2 = fmaxf(hi2, __shfl_xor(hi2, m));
    float d2 = __shfl_xor(best, m); int i2 = __shfl_xor(bi, m);
    if (d2 < best || (d2 == best && i2 < bi)) { best = d2; bi = i2; }
  }

  {
    float s = 0.f;
    for (int j = 0; j < 24; ++j) s += sw[bi*24 + j] * bpf[j*64 + l];
    gin[l] = s;
  }
  if (l < 3) {
    float lo = (l == 0) ? lo0 : (l == 1) ? lo1 : lo2;
    float hi = (l == 0) ? hi0 : (l == 1) ? hi1 : hi2;
    float jc = (l == 0) ? jx : (l == 1) ? jy : jz;
    in2[l] = 2.f * (jc - lo) / (hi - lo + 1e-6f) - 1.f;
  }
  __syncthreads();

  {
    float s = b_body[l];
    for (int t = 0; t < 128; ++t) s += gin[t] * w_body[t*64 + l];
    float u = 0.7978845608028654f * (s + 0.044715f * s * s * s);
    float e = __expf(2.f * u);
    float th = 1.f - 2.f / (e + 1.f);
    in2[3 + l] = 0.5f * s * (1.f + th);
  }
  __syncthreads();

#pragma unroll
  for (int half = 0; half < 2; ++half) {
    const int m = l + 64*half;
    float s = b_pos1[m];
    for (int t = 0; t < 67; ++t) s += in2[t] * w_pos1[t*128 + m];
    h2[m] = fmaxf(s, 0.f);
  }
  __syncthreads();

  {
    float s = b_pos2[l];
    for (int t = 0; t < 128; ++t) s += h2[t] * w_pos2[t*64 + l];
    g2[l] = s;
  }
  __syncthreads();

  if (l < 4) {
    float s = b_rot[l];
    for (int t = 0; t < 64; ++t) s += g2[t] * w_rot[t*4 + l];
    q7[l] = s;
  } else if (l < 7) {
    const int j = l - 4;
    float s = b_trans[j];
    for (int t = 0; t < 64; ++t) s += g2[t] * w_trans[t*3 + j];
    q7[l] = s;
  }
  __syncthreads();
  if (l == 0) {
    float q0 = q7[0], q1 = q7[1], q2 = q7[2], q3 = q7[3];
    float rn = 1.f / (sqrtf(q0*q0 + q1*q1 + q2*q2 + q3*q3) + 1e-6f);
    *(float4*)&qpack[k*4] = make_float4(q0*rn, q1*rn, q2*rn, q3*rn);
    *(float4*)&tpack[k*4] = make_float4(q7[4], q7[5], q7[6], 0.f);
    *(float4*)&jpack[k*4] = make_float4(jx, jy, jz, jx*jx + jy*jy + jz*jz);
  }
}

// ---------------------------------------------------------------------------
// kC: per-point joint softmax + quaternion blend (joint tables in LDS)
// ---------------------------------------------------------------------------
__global__ __launch_bounds__(256) void kC(
    const float* __restrict__ xyz, const float* __restrict__ jpack,
    const float* __restrict__ qpack, const float* __restrict__ tpack,
    float* __restrict__ out)
{
  __shared__ float4 sj[NJ], sq[NJ], st[NJ];
  const int tid = threadIdx.x;
  if (tid < 80)        sj[tid]       = ((const float4*)jpack)[tid];
  else if (tid < 160)  sq[tid - 80]  = ((const float4*)qpack)[tid - 80];
  else if (tid < 240)  st[tid - 160] = ((const float4*)tpack)[tid - 160];
  __syncthreads();

  const int p = blockIdx.x * 256 + tid;
  if (p >= N_PTS) return;

  float x0 = xyz[p*3], x1 = xyz[p*3+1], x2 = xyz[p*3+2];
  float lv[NJ];
  float m = -1e30f;
#pragma unroll
  for (int k = 0; k < NJ; ++k) {
    float4 j = sj[k];
    lv[k] = (2.f*(x0*j.x + x1*j.y + x2*j.z) - j.w) * 10.0f;  // 1/SIGMA
    m = fmaxf(m, lv[k]);
  }
  float s = 0.f;
  float qb0=0,qb1=0,qb2=0,qb3=0, tb0=0,tb1=0,tb2=0;
#pragma unroll
  for (int k = 0; k < NJ; ++k) {
    float e = __expf(lv[k] - m);
    s += e;
    float4 q = sq[k];
    float4 t = st[k];
    qb0 += e*q.x; qb1 += e*q.y; qb2 += e*q.z; qb3 += e*q.w;
    tb0 += e*t.x; tb1 += e*t.y; tb2 += e*t.z;
  }
  float rs = 1.f / s;
  qb0*=rs; qb1*=rs; qb2*=rs; qb3*=rs; tb0*=rs; tb1*=rs; tb2*=rs;
  float nrm = sqrtf(qb0*qb0+qb1*qb1+qb2*qb2+qb3*qb3) + 1e-6f;
  float rn = 1.f / nrm;
  float qw = qb0*rn, qx = qb1*rn, qy = qb2*rn, qz = qb3*rn;
  float t2x = 2.f*(qy*x2 - qz*x1);
  float t2y = 2.f*(qz*x0 - qx*x2);
  float t2z = 2.f*(qx*x1 - qy*x0);
  float cx = qy*t2z - qz*t2y;
  float cy = qz*t2x - qx*t2z;
  float cz = qx*t2y - qy*t2x;
  out[p*3]   = x0 + qw*t2x + cx + tb0;
  out[p*3+1] = x1 + qw*t2y + cy + tb1;
  out[p*3+2] = x2 + qw*t2z + cz + tb2;
}

// ---------------------------------------------------------------------------
extern "C" void kernel_launch(void* const* d_in, const int* in_sizes, int n_in,
                              void* d_out, int out_size, void* d_ws, size_t ws_size,
                              hipStream_t stream) {
  const float* xyz     = (const float*)d_in[0];
  const float* feature = (const float*)d_in[1];
  const float* centers = (const float*)d_in[2];
  const float* smpl    = (const float*)d_in[3];
  const float* sw      = (const float*)d_in[4];
  const float* bpf     = (const float*)d_in[5];
  const float* w_body  = (const float*)d_in[6];
  const float* b_body  = (const float*)d_in[7];
  const float* w_pos1  = (const float*)d_in[8];
  const float* b_pos1  = (const float*)d_in[9];
  const float* w_pos2  = (const float*)d_in[10];
  const float* b_pos2  = (const float*)d_in[11];
  const float* w_rot   = (const float*)d_in[12];
  const float* b_rot   = (const float*)d_in[13];
  const float* w_trans = (const float*)d_in[14];
  const float* b_trans = (const float*)d_in[15];
  float* out = (float*)d_out;

  float* ws    = (float*)d_ws;
  float* jacc  = ws;                  // 5440
  float* jpack = ws + 5440;           // 320
  float* qpack = ws + 5760;           // 320
  float* tpack = ws + 6080;           // 320
  float* part  = ws + 6400;           // GRID_A * 5440 (if it fits)

  const size_t need = (size_t)6400 + (size_t)GRID_A * 5440;
  const bool use_part = (ws_size / 4) >= need;
  float* part_arg = use_part ? part : nullptr;

  hipMemsetAsync(jacc, 0, 5440 * sizeof(float), stream);
  kA<<<dim3(GRID_A), dim3(512), 0, stream>>>(xyz, feature, centers, jacc, part_arg);
  if (use_part)
    kR<<<dim3(22 * RSLICE), dim3(256), 0, stream>>>(part, jacc);
  kB<<<dim3(NJ), dim3(64), 0, stream>>>(jacc, smpl, sw, bpf,
                                        w_body, b_body, w_pos1, b_pos1,
                                        w_pos2, b_pos2, w_rot, b_rot,
                                        w_trans, b_trans, jpack, qpack, tpack);
  kC<<<dim3((N_PTS + 255) / 256), dim3(256), 0, stream>>>(xyz, jpack, qpack, tpack, out);
}

// Round 7
// 135.483 us; speedup vs baseline: 4.2893x; 1.1647x over previous
//
#include <hip/hip_runtime.h>
#include <math.h>

#define N_PTS 300000
#define NJ 80          // K joints
#define FDIM 64        // feature dim
#define VN 6890        // smpl verts
#define NROUND 9375    // 300000 / 32  (exact)
#define GRID_A 512
#define WAVES_A (GRID_A * 4)

typedef __attribute__((ext_vector_type(8))) short short8;
typedef __attribute__((ext_vector_type(4))) float f32x4;

union Frag { uint32_t u[4]; short8 v; };

// hi-pair pack: two f32 -> one u32 of two bf16 (truncated)
__device__ __forceinline__ uint32_t packhi(float a, float b) {
  return (__float_as_uint(a) >> 16) | (__float_as_uint(b) & 0xFFFF0000u);
}
// residual-lo pair pack
__device__ __forceinline__ uint32_t packlo(float a, float b) {
  float la = a - __uint_as_float(__float_as_uint(a) & 0xFFFF0000u);
  float lb = b - __uint_as_float(__float_as_uint(b) & 0xFFFF0000u);
  return packhi(la, lb);
}

// DPP cross-lane (VALU pipe, within row-16): quad_perm xor1/xor2 + mirrors
#define DPPF(x, ctrl) __uint_as_float((uint32_t)__builtin_amdgcn_update_dpp( \
    0, (int)__float_as_uint(x), (ctrl), 0xF, 0xF, true))

// ---------------------------------------------------------------------------
// kA: barrier-free per-wave pipeline over 32-pt rounds:
//   GEMM1: A = feature (global, coalesced, hi/lo split), B = centers
//          (hi in regs, lo in LDS) -> logits via 3-term bf16 MFMA.
//   softmax: DPP butterflies (max & sum over 16 lanes), all VALU-pipe.
//   P stays in registers == A-fragment of GEMM2 (swapped-operand trick).
//   D^T (bf16-hi) written to wave-PRIVATE LDS tile; GEMM2 = 25 MFMA
//   16x16x32 into persistent acc2[5][5]. No __syncthreads in main loop.
// Epilogue: block LDS-reduce -> per-block partials (kR reduces) or atomics.
// ---------------------------------------------------------------------------
__global__ __launch_bounds__(256, 2) void kA(
    const float* __restrict__ xyz, const float* __restrict__ feature,
    const float* __restrict__ centers, float* __restrict__ jacc,
    float* __restrict__ part)
{
  __shared__ ushort sClo[NJ][72];      // centers residual-lo bf16
  __shared__ ushort sT[4][NJ][36];     // per-wave D^T tile [dim][pt32]; rows 68..79 zero

  const int tid = threadIdx.x;
  const int w = tid >> 6;        // wave 0..3
  const int l = tid & 63;
  const int i = l & 15;          // lane-in-16
  const int g = l >> 4;          // quarter-group 0..3

  // zero sT (rows >= 68 must stay zero; rest rewritten every round)
  for (int idx = tid; idx < 4 * NJ * 36; idx += 256) ((ushort*)sT)[idx] = 0;
  // centers residual-lo
  for (int idx = tid; idx < NJ * FDIM; idx += 256) {
    float f = centers[idx];
    float lo = f - __uint_as_float(__float_as_uint(f) & 0xFFFF0000u);
    sClo[idx >> 6][idx & 63] = (ushort)(__float_as_uint(lo) >> 16);
  }

  // centers-hi B-frags in registers + |c|^2
  Frag bh[5][2];
  float cn[5];
#pragma unroll
  for (int nt = 0; nt < 5; ++nt) {
    float s = 0.f;
#pragma unroll
    for (int ks = 0; ks < 2; ++ks) {
      const float4* cp = (const float4*)(centers + (size_t)(i + 16*nt) * FDIM + 32*ks + 8*g);
      float4 v0 = cp[0], v1 = cp[1];
      bh[nt][ks].u[0] = packhi(v0.x, v0.y);
      bh[nt][ks].u[1] = packhi(v0.z, v0.w);
      bh[nt][ks].u[2] = packhi(v1.x, v1.y);
      bh[nt][ks].u[3] = packhi(v1.z, v1.w);
      s += v0.x*v0.x + v0.y*v0.y + v0.z*v0.z + v0.w*v0.w
         + v1.x*v1.x + v1.y*v1.y + v1.z*v1.z + v1.w*v1.w;
    }
    s += __shfl_xor(s, 16);
    s += __shfl_xor(s, 32);
    cn[nt] = s;
  }

  f32x4 acc2[5][5];
#pragma unroll
  for (int a = 0; a < 5; ++a)
#pragma unroll
    for (int b = 0; b < 5; ++b) acc2[a][b] = (f32x4){0.f, 0.f, 0.f, 0.f};

  __syncthreads();   // sClo / sT ready

  const int gw = blockIdx.x * 4 + w;
  for (int rd = gw; rd < NROUND; rd += WAVES_A) {
    const int pbase = rd * 32;

    // -------- issue ALL global loads for the round up-front --------
    float4 vv[2][2][2];     // [chunk][ks][half]
    float  xq[2];
#pragma unroll
    for (int c = 0; c < 2; ++c) {
      const int pt = pbase + 16*c + i;
#pragma unroll
      for (int ks = 0; ks < 2; ++ks) {
        const float4* fp = (const float4*)(feature + (size_t)pt * FDIM + 32*ks + 8*g);
        vv[c][ks][0] = fp[0];
        vv[c][ks][1] = fp[1];
      }
      xq[c] = (g < 3) ? xyz[(size_t)pt * 3 + g] : 1.0f;
    }

    Frag pA[5];
#pragma unroll
    for (int c = 0; c < 2; ++c) {
      f32x4 acc1[5];
#pragma unroll
      for (int nt = 0; nt < 5; ++nt) acc1[nt] = (f32x4){0.f, 0.f, 0.f, 0.f};

#pragma unroll
      for (int ks = 0; ks < 2; ++ks) {
        float4 v0 = vv[c][ks][0], v1 = vv[c][ks][1];
        Frag ah, al;
        ah.u[0] = packhi(v0.x, v0.y); ah.u[1] = packhi(v0.z, v0.w);
        ah.u[2] = packhi(v1.x, v1.y); ah.u[3] = packhi(v1.z, v1.w);
        al.u[0] = packlo(v0.x, v0.y); al.u[1] = packlo(v0.z, v0.w);
        al.u[2] = packlo(v1.x, v1.y); al.u[3] = packlo(v1.z, v1.w);
        // D^T stage (bf16-hi, transposed, wave-private)
        const int d0 = 32*ks + 8*g, pcol = 16*c + i;
        sT[w][d0+0][pcol] = (ushort)(ah.u[0] & 0xFFFFu);
        sT[w][d0+1][pcol] = (ushort)(ah.u[0] >> 16);
        sT[w][d0+2][pcol] = (ushort)(ah.u[1] & 0xFFFFu);
        sT[w][d0+3][pcol] = (ushort)(ah.u[1] >> 16);
        sT[w][d0+4][pcol] = (ushort)(ah.u[2] & 0xFFFFu);
        sT[w][d0+5][pcol] = (ushort)(ah.u[2] >> 16);
        sT[w][d0+6][pcol] = (ushort)(ah.u[3] & 0xFFFFu);
        sT[w][d0+7][pcol] = (ushort)(ah.u[3] >> 16);
#pragma unroll
        for (int nt = 0; nt < 5; ++nt) {
          Frag bl;
          *(uint4*)bl.u = *(const uint4*)&sClo[i + 16*nt][32*ks + 8*g];
          acc1[nt] = __builtin_amdgcn_mfma_f32_16x16x32_bf16(ah.v, bh[nt][ks].v, acc1[nt], 0, 0, 0);
          acc1[nt] = __builtin_amdgcn_mfma_f32_16x16x32_bf16(al.v, bh[nt][ks].v, acc1[nt], 0, 0, 0);
          acc1[nt] = __builtin_amdgcn_mfma_f32_16x16x32_bf16(ah.v, bl.v,        acc1[nt], 0, 0, 0);
        }
      }
      // xyz rows 64..66 and ones row 67 (g==3 -> 64+3 = 67)
      sT[w][64 + g][16*c + i] =
          (g < 3) ? (ushort)(__float_as_uint(xq[c]) >> 16) : (ushort)0x3F80;

      // -------- softmax (DPP butterflies over the 16 i-lanes) --------
      f32x4 e5[5];
#pragma unroll
      for (int nt = 0; nt < 5; ++nt) {
#pragma unroll
        for (int r = 0; r < 4; ++r) e5[nt][r] = 2.f * acc1[nt][r] - cn[nt];
      }
      float rs[4];
#pragma unroll
      for (int r = 0; r < 4; ++r) {
        float m = e5[0][r];
#pragma unroll
        for (int nt = 1; nt < 5; ++nt) m = fmaxf(m, e5[nt][r]);
        m = fmaxf(m, DPPF(m, 0xB1));    // quad_perm xor1
        m = fmaxf(m, DPPF(m, 0x4E));    // quad_perm xor2
        m = fmaxf(m, DPPF(m, 0x141));   // row_half_mirror
        m = fmaxf(m, DPPF(m, 0x140));   // row_mirror
        float s = 0.f;
#pragma unroll
        for (int nt = 0; nt < 5; ++nt) {
          float e = __expf(e5[nt][r] - m);
          e5[nt][r] = e;
          s += e;
        }
        s += DPPF(s, 0xB1);
        s += DPPF(s, 0x4E);
        s += DPPF(s, 0x141);
        s += DPPF(s, 0x140);
        rs[r] = __builtin_amdgcn_rcpf(s);
      }
      // P -> GEMM2 A-frag halves (chunk c fills u[2c], u[2c+1])
#pragma unroll
      for (int nt = 0; nt < 5; ++nt) {
        pA[nt].u[2*c + 0] = packhi(e5[nt][0] * rs[0], e5[nt][1] * rs[1]);
        pA[nt].u[2*c + 1] = packhi(e5[nt][2] * rs[2], e5[nt][3] * rs[3]);
      }
    } // chunk

    // -------- GEMM2: jacc[joint][col] += P * D (wave-private T) --------
#pragma unroll
    for (int ct = 0; ct < 5; ++ct) {
      Frag B;
      *(uint2*)&B.u[0] = *(const uint2*)&sT[w][16*ct + i][4*g];
      *(uint2*)&B.u[2] = *(const uint2*)&sT[w][16*ct + i][16 + 4*g];
#pragma unroll
      for (int nt = 0; nt < 5; ++nt)
        acc2[nt][ct] = __builtin_amdgcn_mfma_f32_16x16x32_bf16(pA[nt].v, B.v, acc2[nt][ct], 0, 0, 0);
    }
  } // rounds

  // -------- epilogue: block-reduce in LDS (alias over sT), then store ------
  __syncthreads();
  float* sJ = (float*)&sT[0][0][0];    // 23040B >= 5440*4B
  for (int idx = tid; idx < 5440; idx += 256) sJ[idx] = 0.f;
  __syncthreads();
#pragma unroll
  for (int ww = 0; ww < 4; ++ww) {
    if (w == ww) {
#pragma unroll
      for (int nt = 0; nt < 5; ++nt)
#pragma unroll
        for (int ct = 0; ct < 5; ++ct) {
          if (ct < 4 || i < 4) {
            const int col = 16*ct + i;
#pragma unroll
            for (int r = 0; r < 4; ++r)
              sJ[(16*nt + 4*g + r) * 68 + col] += acc2[nt][ct][r];
          }
        }
    }
    __syncthreads();
  }
  if (part) {
    for (int idx = tid; idx < 5440; idx += 256)
      part[(size_t)blockIdx.x * 5440 + idx] = sJ[idx];
  } else {
    for (int idx = tid; idx < 5440; idx += 256)
      atomicAdd(&jacc[idx], sJ[idx]);
  }
}

// ---------------------------------------------------------------------------
// kR: jacc[t] += sum over 512 block partials (16 slices x 32)
// ---------------------------------------------------------------------------
__global__ __launch_bounds__(256) void kR(const float* __restrict__ part,
                                          float* __restrict__ jacc)
{
  const int bx = blockIdx.x;
  const int cg = bx % 22, sl = bx / 22;
  const int t = cg * 256 + threadIdx.x;
  if (t >= 5440) return;
  const int b0 = sl * 32;
  float s0 = 0.f, s1 = 0.f, s2 = 0.f, s3 = 0.f;
  for (int b = b0; b < b0 + 32; b += 4) {
    s0 += part[(size_t)(b+0) * 5440 + t];
    s1 += part[(size_t)(b+1) * 5440 + t];
    s2 += part[(size_t)(b+2) * 5440 + t];
    s3 += part[(size_t)(b+3) * 5440 + t];
  }
  atomicAdd(&jacc[t], (s0 + s1) + (s2 + s3));
}

// ---------------------------------------------------------------------------
// kB: one block (1 wave) per joint: finalize, lo/hi, argmin, full MLP chain
// ---------------------------------------------------------------------------
__global__ __launch_bounds__(64) void kB(
    const float* __restrict__ jacc, const float* __restrict__ smpl,
    const float* __restrict__ sw, const float* __restrict__ bpf,
    const float* __restrict__ w_body, const float* __restrict__ b_body,
    const float* __restrict__ w_pos1, const float* __restrict__ b_pos1,
    const float* __restrict__ w_pos2, const float* __restrict__ b_pos2,
    const float* __restrict__ w_rot,  const float* __restrict__ b_rot,
    const float* __restrict__ w_trans,const float* __restrict__ b_trans,
    float* __restrict__ jpack, float* __restrict__ qpack,
    float* __restrict__ tpack)
{
  const int k = blockIdx.x;
  const int l = threadIdx.x;
  __shared__ float gin[128];
  __shared__ float in2[67];
  __shared__ float h2[128];
  __shared__ float g2[64];
  __shared__ float q7[8];

  const float cnt = jacc[k*68 + 67] + 1e-6f;
  gin[64 + l] = jacc[k*68 + l] / cnt;
  const float jx = jacc[k*68 + 64] / cnt;
  const float jy = jacc[k*68 + 65] / cnt;
  const float jz = jacc[k*68 + 66] / cnt;

  float lo0 = 1e30f, lo1 = 1e30f, lo2 = 1e30f;
  float hi0 = -1e30f, hi1 = -1e30f, hi2 = -1e30f;
  float best = 1e30f; int bi = 0;
  for (int v = l; v < VN; v += 64) {
    float x = smpl[v*3], y = smpl[v*3+1], z = smpl[v*3+2];
    lo0 = fminf(lo0, x); hi0 = fmaxf(hi0, x);
    lo1 = fminf(lo1, y); hi1 = fmaxf(hi1, y);
    lo2 = fminf(lo2, z); hi2 = fmaxf(hi2, z);
    float dx = x - jx, dy = y - jy, dz = z - jz;
    float d = dx*dx + dy*dy + dz*dz;
    if (d < best) { best = d; bi = v; }
  }
#pragma unroll
  for (int m = 1; m < 64; m <<= 1) {
    lo0 = fminf(lo0, __shfl_xor(lo0, m));
    lo1 = fminf(lo1, __shfl_xor(lo1, m));
    lo2 = fminf(lo2, __shfl_xor(lo2, m));
    hi0 = fmaxf(hi0, __shfl_xor(hi0, m));
    hi1 = fmaxf(hi1, __shfl_xor(hi1, m));
    hi2 = fmaxf(hi2, __shfl_xor(hi2, m));
    float d2 = __shfl_xor(best, m); int i2 = __shfl_xor(bi, m);
    if (d2 < best || (d2 == best && i2 < bi)) { best = d2; bi = i2; }
  }

  {
    float s = 0.f;
    for (int j = 0; j < 24; ++j) s += sw[bi*24 + j] * bpf[j*64 + l];
    gin[l] = s;
  }
  if (l < 3) {
    float lo = (l == 0) ? lo0 : (l == 1) ? lo1 : lo2;
    float hi = (l == 0) ? hi0 : (l == 1) ? hi1 : hi2;
    float jc = (l == 0) ? jx : (l == 1) ? jy : jz;
    in2[l] = 2.f * (jc - lo) / (hi - lo + 1e-6f) - 1.f;
  }
  __syncthreads();

  {
    float s = b_body[l];
    for (int t = 0; t < 128; ++t) s += gin[t] * w_body[t*64 + l];
    float u = 0.7978845608028654f * (s + 0.044715f * s * s * s);
    float e = __expf(2.f * u);
    float th = 1.f - 2.f / (e + 1.f);
    in2[3 + l] = 0.5f * s * (1.f + th);
  }
  __syncthreads();

#pragma unroll
  for (int half = 0; half < 2; ++half) {
    const int m = l + 64*half;
    float s = b_pos1[m];
    for (int t = 0; t < 67; ++t) s += in2[t] * w_pos1[t*128 + m];
    h2[m] = fmaxf(s, 0.f);
  }
  __syncthreads();

  {
    float s = b_pos2[l];
    for (int t = 0; t < 128; ++t) s += h2[t] * w_pos2[t*64 + l];
    g2[l] = s;
  }
  __syncthreads();

  if (l < 4) {
    float s = b_rot[l];
    for (int t = 0; t < 64; ++t) s += g2[t] * w_rot[t*4 + l];
    q7[l] = s;
  } else if (l < 7) {
    const int j = l - 4;
    float s = b_trans[j];
    for (int t = 0; t < 64; ++t) s += g2[t] * w_trans[t*3 + j];
    q7[l] = s;
  }
  __syncthreads();
  if (l == 0) {
    float q0 = q7[0], q1 = q7[1], q2 = q7[2], q3 = q7[3];
    float rn = 1.f / (sqrtf(q0*q0 + q1*q1 + q2*q2 + q3*q3) + 1e-6f);
    *(float4*)&qpack[k*4] = make_float4(q0*rn, q1*rn, q2*rn, q3*rn);
    *(float4*)&tpack[k*4] = make_float4(q7[4], q7[5], q7[6], 0.f);
    *(float4*)&jpack[k*4] = make_float4(jx, jy, jz, jx*jx + jy*jy + jz*jz);
  }
}

// ---------------------------------------------------------------------------
// kC: per-point joint softmax + quaternion blend (joint tables in LDS)
// ---------------------------------------------------------------------------
__global__ __launch_bounds__(256) void kC(
    const float* __restrict__ xyz, const float* __restrict__ jpack,
    const float* __restrict__ qpack, const float* __restrict__ tpack,
    float* __restrict__ out)
{
  __shared__ float4 sj[NJ], sq[NJ], st[NJ];
  const int tid = threadIdx.x;
  if (tid < 80)        sj[tid]       = ((const float4*)jpack)[tid];
  else if (tid < 160)  sq[tid - 80]  = ((const float4*)qpack)[tid - 80];
  else if (tid < 240)  st[tid - 160] = ((const float4*)tpack)[tid - 160];
  __syncthreads();

  const int p = blockIdx.x * 256 + tid;
  if (p >= N_PTS) return;

  float x0 = xyz[p*3], x1 = xyz[p*3+1], x2 = xyz[p*3+2];
  float lv[NJ];
  float m = -1e30f;
#pragma unroll
  for (int k = 0; k < NJ; ++k) {
    float4 j = sj[k];
    lv[k] = (2.f*(x0*j.x + x1*j.y + x2*j.z) - j.w) * 10.0f;  // 1/SIGMA
    m = fmaxf(m, lv[k]);
  }
  float s = 0.f;
  float qb0=0,qb1=0,qb2=0,qb3=0, tb0=0,tb1=0,tb2=0;
#pragma unroll
  for (int k = 0; k < NJ; ++k) {
    float e = __expf(lv[k] - m);
    s += e;
    float4 q = sq[k];
    float4 t = st[k];
    qb0 += e*q.x; qb1 += e*q.y; qb2 += e*q.z; qb3 += e*q.w;
    tb0 += e*t.x; tb1 += e*t.y; tb2 += e*t.z;
  }
  float rs = 1.f / s;
  qb0*=rs; qb1*=rs; qb2*=rs; qb3*=rs; tb0*=rs; tb1*=rs; tb2*=rs;
  float nrm = sqrtf(qb0*qb0+qb1*qb1+qb2*qb2+qb3*qb3) + 1e-6f;
  float rn = 1.f / nrm;
  float qw = qb0*rn, qx = qb1*rn, qy = qb2*rn, qz = qb3*rn;
  float t2x = 2.f*(qy*x2 - qz*x1);
  float t2y = 2.f*(qz*x0 - qx*x2);
  float t2z = 2.f*(qx*x1 - qy*x0);
  float cx = qy*t2z - qz*t2y;
  float cy = qz*t2x - qx*t2z;
  float cz = qx*t2y - qy*t2x;
  out[p*3]   = x0 + qw*t2x + cx + tb0;
  out[p*3+1] = x1 + qw*t2y + cy + tb1;
  out[p*3+2] = x2 + qw*t2z + cz + tb2;
}

// ---------------------------------------------------------------------------
extern "C" void kernel_launch(void* const* d_in, const int* in_sizes, int n_in,
                              void* d_out, int out_size, void* d_ws, size_t ws_size,
                              hipStream_t stream) {
  const float* xyz     = (const float*)d_in[0];
  const float* feature = (const float*)d_in[1];
  const float* centers = (const float*)d_in[2];
  const float* smpl    = (const float*)d_in[3];
  const float* sw      = (const float*)d_in[4];
  const float* bpf     = (const float*)d_in[5];
  const float* w_body  = (const float*)d_in[6];
  const float* b_body  = (const float*)d_in[7];
  const float* w_pos1  = (const float*)d_in[8];
  const float* b_pos1  = (const float*)d_in[9];
  const float* w_pos2  = (const float*)d_in[10];
  const float* b_pos2  = (const float*)d_in[11];
  const float* w_rot   = (const float*)d_in[12];
  const float* b_rot   = (const float*)d_in[13];
  const float* w_trans = (const float*)d_in[14];
  const float* b_trans = (const float*)d_in[15];
  float* out = (float*)d_out;

  float* ws    = (float*)d_ws;
  float* jacc  = ws;                  // 5440
  float* jpack = ws + 5440;           // 320
  float* qpack = ws + 5760;           // 320
  float* tpack = ws + 6080;           // 320
  float* part  = ws + 6400;           // GRID_A * 5440 (if it fits)

  const size_t need = (size_t)6400 + (size_t)GRID_A * 5440;
  const bool use_part = (ws_size / 4) >= need;
  float* part_arg = use_part ? part : nullptr;

  hipMemsetAsync(jacc, 0, 5440 * sizeof(float), stream);
  kA<<<dim3(GRID_A), dim3(256), 0, stream>>>(xyz, feature, centers, jacc, part_arg);
  if (use_part)
    kR<<<dim3(22 * 16), dim3(256), 0, stream>>>(part, jacc);
  kB<<<dim3(NJ), dim3(64), 0, stream>>>(jacc, smpl, sw, bpf,
                                        w_body, b_body, w_pos1, b_pos1,
                                        w_pos2, b_pos2, w_rot, b_rot,
                                        w_trans, b_trans, jpack, qpack, tpack);
  kC<<<dim3((N_PTS + 255) / 256), dim3(256), 0, stream>>>(xyz, jpack, qpack, tpack, out);
}